// Round 1
// baseline (305.551 us; speedup 1.0000x reference)
//
#include <hip/hip_runtime.h>

// LambdaLayer2D: B=16, C=256, H=W=64, K=16, HEADS=4, U=1, V=64, R=7
#define B_ 16
#define C_ 256
#define N_ 4096            // H*W
#define NT_ 65536          // B*N
#define M_ 144             // 64 q-rows + 16 k-rows + 64 v-rows

typedef _Float16 f16x8 __attribute__((ext_vector_type(8)));
typedef _Float16 f16x4 __attribute__((ext_vector_type(4)));
typedef float    f32x4 __attribute__((ext_vector_type(4)));

__device__ __forceinline__ float waveSum(float v){
  #pragma unroll
  for (int off = 32; off > 0; off >>= 1) v += __shfl_xor(v, off, 64);
  return v;
}
__device__ __forceinline__ float waveMax(float v){
  #pragma unroll
  for (int off = 32; off > 0; off >>= 1) v = fmaxf(v, __shfl_xor(v, off, 64));
  return v;
}

// ---------------- K0: pack Wq|Wk|Wv -> fp16 [144][256] ----------------
__global__ void k_pack_w(const float* __restrict__ Wq, const float* __restrict__ Wk,
                         const float* __restrict__ Wv, _Float16* __restrict__ Wcat){
  int idx = blockIdx.x * 256 + threadIdx.x;   // 144*256 = 36864
  int row = idx >> 8, col = idx & 255;
  float v;
  if (row < 64)      v = Wq[row * 256 + col];
  else if (row < 80) v = Wk[(row - 64) * 256 + col];
  else               v = Wv[(row - 80) * 256 + col];
  Wcat[idx] = (_Float16)v;
}

// ---------------- K1: projection GEMM P[144][65536] = Wcat @ X -------
// One wave per 16-pixel column tile; wave computes all 9 row-tiles (full
// W reuse; x read exactly once). mfma_f32_16x16x32_f16, fp32 accum.
__global__ __launch_bounds__(256) void k_proj(const float* __restrict__ x,
                                              const _Float16* __restrict__ Wcat,
                                              float* __restrict__ P){
  const int lane = threadIdx.x & 63;
  const int wid  = threadIdx.x >> 6;
  const int tile = blockIdx.x * 4 + wid;   // 0..4095
  const int j0 = tile << 4;
  const int b  = j0 >> 12;
  const int n0 = j0 & 4095;
  const int cl = lane & 15;                // A-row / B-col / D-col index
  const int kg = lane >> 4;                // k-group

  f32x4 acc[9];
  #pragma unroll
  for (int m = 0; m < 9; ++m){ acc[m][0]=0.f; acc[m][1]=0.f; acc[m][2]=0.f; acc[m][3]=0.f; }

  const float* xb = x + (size_t)b * C_ * N_ + n0 + cl;
  #pragma unroll
  for (int kk = 0; kk < 8; ++kk){
    const int kb = kk * 32 + kg * 8;
    f16x8 bfrag;                                   // B[k][col]: k = kb..kb+7
    #pragma unroll
    for (int jj = 0; jj < 8; ++jj) bfrag[jj] = (_Float16)xb[(size_t)(kb + jj) * N_];
    #pragma unroll
    for (int m = 0; m < 9; ++m){                   // A[row][k], 16B aligned load
      f16x8 afrag = *reinterpret_cast<const f16x8*>(Wcat + ((m * 16 + cl) << 8) + kb);
      acc[m] = __builtin_amdgcn_mfma_f32_16x16x32_f16(afrag, bfrag, acc[m], 0, 0, 0);
    }
  }
  // D: col = lane&15, row = (lane>>4)*4 + r  (guide-verified layout)
  float* Pw = P + j0 + cl;
  #pragma unroll
  for (int m = 0; m < 9; ++m){
    #pragma unroll
    for (int r = 0; r < 4; ++r){
      int o = m * 16 + kg * 4 + r;
      Pw[(size_t)o * NT_] = acc[m][r];
    }
  }
}

// ---------------- K2a: BN stats -> folded affine (a, c) --------------
// stats layout: [0:64) aq, [64:128) cq, [128:192) av, [192:256) cv
__global__ void k_bnstats(const float* __restrict__ P,
                          const float* __restrict__ gq, const float* __restrict__ bq,
                          const float* __restrict__ gv, const float* __restrict__ bv,
                          float* __restrict__ stats){
  const int ch = blockIdx.x;                    // 0..127
  const int o = (ch < 64) ? ch : (80 + (ch - 64));
  const float* row = P + (size_t)o * NT_;
  float s = 0.f, ss = 0.f;
  for (int i = threadIdx.x; i < NT_; i += 256){ float v = row[i]; s += v; ss += v * v; }
  __shared__ float r0[4], r1[4];
  const int lane = threadIdx.x & 63, wid = threadIdx.x >> 6;
  s = waveSum(s); ss = waveSum(ss);
  if (lane == 0){ r0[wid] = s; r1[wid] = ss; }
  __syncthreads();
  if (threadIdx.x == 0){
    s  = r0[0] + r0[1] + r0[2] + r0[3];
    ss = r1[0] + r1[1] + r1[2] + r1[3];
    float mean = s * (1.f / NT_);
    float var  = ss * (1.f / NT_) - mean * mean;   // biased
    float rs = rsqrtf(var + 1e-5f);
    if (ch < 64){
      float a = rs * gq[ch];
      stats[ch] = a; stats[64 + ch] = bq[ch] - mean * a;
    } else {
      int v = ch - 64;
      float a = rs * gv[v];
      stats[128 + v] = a; stats[192 + v] = bv[v] - mean * a;
    }
  }
}

// ---------------- K2b: softmax row stats (max, 1/sumexp) -------------
__global__ void k_softstats(const float* __restrict__ P, float* __restrict__ kstat){
  const int bid = blockIdx.x;                   // b*16 + kc
  const int b = bid >> 4, kc = bid & 15;
  const float* row = P + (size_t)(64 + kc) * NT_ + b * N_;
  const int lane = threadIdx.x & 63, wid = threadIdx.x >> 6;
  __shared__ float sm[4], sb[4];
  float m = -1e30f;
  for (int i = threadIdx.x; i < N_; i += 256) m = fmaxf(m, row[i]);
  m = waveMax(m);
  if (lane == 0) sm[wid] = m;
  __syncthreads();
  float mg = fmaxf(fmaxf(sm[0], sm[1]), fmaxf(sm[2], sm[3]));
  float s = 0.f;
  for (int i = threadIdx.x; i < N_; i += 256) s += __expf(row[i] - mg);
  s = waveSum(s);
  if (lane == 0) sb[wid] = s;
  __syncthreads();
  if (threadIdx.x == 0){
    float st = sb[0] + sb[1] + sb[2] + sb[3];
    kstat[bid] = mg;
    kstat[256 + bid] = 1.f / st;
  }
}

// ---------------- K3: lambda_c[b][kc][v] = av*sum(sk*Pv) + cv --------
// (uses sum(softmax)=1 to fold the BN affine of v)
__global__ __launch_bounds__(256) void k_lambda(const float* __restrict__ P,
                          const float* __restrict__ stats,
                          const float* __restrict__ kstat,
                          float* __restrict__ lc){
  const int bid = blockIdx.x;                   // b*16 + kc
  const int b = bid >> 4, kc = bid & 15;
  const int lane = threadIdx.x & 63, g = threadIdx.x >> 6;  // g: v-group of 16
  const float* krow = P + (size_t)(64 + kc) * NT_ + b * N_;
  const float km = kstat[bid], ki = kstat[256 + bid];
  const float* vb = P + (size_t)80 * NT_ + b * N_;
  float S[16];
  #pragma unroll
  for (int i = 0; i < 16; ++i) S[i] = 0.f;
  for (int it = 0; it < 64; ++it){
    int n = lane + it * 64;
    float sk = __expf(krow[n] - km) * ki;
    #pragma unroll
    for (int vv = 0; vv < 16; ++vv) S[vv] += sk * vb[(size_t)(g * 16 + vv) * NT_ + n];
  }
  #pragma unroll
  for (int vv = 0; vv < 16; ++vv){
    float r = waveSum(S[vv]);
    if (lane == 0){
      int v = g * 16 + vv;
      lc[(bid << 6) + v] = stats[128 + v] * r + stats[192 + v];
    }
  }
}

// ---------------- K4: fused positional conv + contractions -----------
// Tile 16x4 pixels per block, 256 thr = 64 px * 4 v-groups.
// y[h,v,n] = sum_k q*lc + q.pos_b + sum_d (sum_k q*w[k,d]) * vn[v,n+d]
__global__ __launch_bounds__(256) void k_final(const float* __restrict__ P,
                        const float* __restrict__ stats,
                        const float* __restrict__ lc,
                        const float* __restrict__ pos_w,
                        const float* __restrict__ pos_b,
                        float* __restrict__ out){
  __shared__ __align__(16) _Float16 vn_s[220][68];  // halo 10x22, v padded to 68
  __shared__ __align__(16) float qs[64][64];        // [ch][pix]
  __shared__ __align__(16) float lc_s[16][64];
  __shared__ __align__(16) float w_s[49][16];       // [tap][k]
  __shared__ float pb_s[16];

  const int b  = blockIdx.z;
  const int x0 = blockIdx.x * 16;
  const int y0 = blockIdx.y * 4;
  const int tid = threadIdx.x;
  const float* Pb = P + (size_t)b * N_;

  for (int f = tid; f < 220 * 64; f += 256){
    int v = f / 220, pos = f - v * 220;
    int yy = pos / 22, xx = pos - yy * 22;
    int gy = y0 + yy - 3, gx = x0 + xx - 3;
    float val = 0.f;                               // 'SAME' zero padding
    if ((unsigned)gy < 64u && (unsigned)gx < 64u)
      val = Pb[(size_t)(80 + v) * NT_ + gy * 64 + gx] * stats[128 + v] + stats[192 + v];
    vn_s[pos][v] = (_Float16)val;
  }
  for (int f = tid; f < 64 * 64; f += 256){
    int c = f >> 6, p = f & 63;
    int py = p >> 4, px = p & 15;
    qs[c][p] = Pb[(size_t)c * NT_ + (y0 + py) * 64 + x0 + px] * stats[c] + stats[64 + c];
  }
  for (int f = tid; f < 1024; f += 256) lc_s[f >> 6][f & 63] = lc[(b << 10) + f];
  for (int f = tid; f < 784; f += 256){ int k = f / 49, t = f - k * 49; w_s[t][k] = pos_w[f]; }
  if (tid < 16) pb_s[tid] = pos_b[tid];
  __syncthreads();

  const int p = tid & 63, g = tid >> 6;
  const int py = p >> 4, px = p & 15;

  float qreg[64];
  #pragma unroll
  for (int c = 0; c < 64; ++c) qreg[c] = qs[c][p];

  float acc[4][16];
  #pragma unroll
  for (int h = 0; h < 4; ++h){
    #pragma unroll
    for (int vv = 0; vv < 16; ++vv) acc[h][vv] = 0.f;
  }

  // content: y_c[h][v] += q[h*16+k] * lc[k][v]
  #pragma unroll
  for (int k = 0; k < 16; ++k){
    float q0 = qreg[k], q1 = qreg[16 + k], q2 = qreg[32 + k], q3 = qreg[48 + k];
    #pragma unroll
    for (int vq = 0; vq < 4; ++vq){
      float4 l4 = *reinterpret_cast<const float4*>(&lc_s[k][g * 16 + vq * 4]);
      acc[0][vq*4+0] += q0*l4.x; acc[0][vq*4+1] += q0*l4.y; acc[0][vq*4+2] += q0*l4.z; acc[0][vq*4+3] += q0*l4.w;
      acc[1][vq*4+0] += q1*l4.x; acc[1][vq*4+1] += q1*l4.y; acc[1][vq*4+2] += q1*l4.z; acc[1][vq*4+3] += q1*l4.w;
      acc[2][vq*4+0] += q2*l4.x; acc[2][vq*4+1] += q2*l4.y; acc[2][vq*4+2] += q2*l4.z; acc[2][vq*4+3] += q2*l4.w;
      acc[3][vq*4+0] += q3*l4.x; acc[3][vq*4+1] += q3*l4.y; acc[3][vq*4+2] += q3*l4.z; acc[3][vq*4+3] += q3*l4.w;
    }
  }
  // bias term: (sum_k q*pos_b[k]) added to every v
  float qb[4];
  #pragma unroll
  for (int h = 0; h < 4; ++h){
    float sbv = 0.f;
    #pragma unroll
    for (int k = 0; k < 16; ++k) sbv += qreg[h * 16 + k] * pb_s[k];
    qb[h] = sbv;
  }

  // positional: per tap, s[h] = sum_k q*w, then rank-1 into acc
  for (int dy = 0; dy < 7; ++dy){
    #pragma unroll
    for (int dx = 0; dx < 7; ++dx){
      const int tap = dy * 7 + dx;
      const int pos = (py + dy) * 22 + (px + dx);
      float s0 = 0.f, s1 = 0.f, s2 = 0.f, s3 = 0.f;
      #pragma unroll
      for (int kq = 0; kq < 4; ++kq){
        float4 w4 = *reinterpret_cast<const float4*>(&w_s[tap][kq * 4]);
        s0 += qreg[ 0+kq*4+0]*w4.x + qreg[ 0+kq*4+1]*w4.y + qreg[ 0+kq*4+2]*w4.z + qreg[ 0+kq*4+3]*w4.w;
        s1 += qreg[16+kq*4+0]*w4.x + qreg[16+kq*4+1]*w4.y + qreg[16+kq*4+2]*w4.z + qreg[16+kq*4+3]*w4.w;
        s2 += qreg[32+kq*4+0]*w4.x + qreg[32+kq*4+1]*w4.y + qreg[32+kq*4+2]*w4.z + qreg[32+kq*4+3]*w4.w;
        s3 += qreg[48+kq*4+0]*w4.x + qreg[48+kq*4+1]*w4.y + qreg[48+kq*4+2]*w4.z + qreg[48+kq*4+3]*w4.w;
      }
      #pragma unroll
      for (int vq = 0; vq < 4; ++vq){
        f16x4 v4 = *reinterpret_cast<const f16x4*>(&vn_s[pos][g * 16 + vq * 4]);
        float f0 = (float)v4[0], f1 = (float)v4[1], f2 = (float)v4[2], f3 = (float)v4[3];
        acc[0][vq*4+0] += s0*f0; acc[0][vq*4+1] += s0*f1; acc[0][vq*4+2] += s0*f2; acc[0][vq*4+3] += s0*f3;
        acc[1][vq*4+0] += s1*f0; acc[1][vq*4+1] += s1*f1; acc[1][vq*4+2] += s1*f2; acc[1][vq*4+3] += s1*f3;
        acc[2][vq*4+0] += s2*f0; acc[2][vq*4+1] += s2*f1; acc[2][vq*4+2] += s2*f2; acc[2][vq*4+3] += s2*f3;
        acc[3][vq*4+0] += s3*f0; acc[3][vq*4+1] += s3*f1; acc[3][vq*4+2] += s3*f2; acc[3][vq*4+3] += s3*f3;
      }
    }
  }

  float* ob = out + (size_t)b * 256 * N_ + (y0 + py) * 64 + (x0 + px);
  #pragma unroll
  for (int h = 0; h < 4; ++h){
    #pragma unroll
    for (int vv = 0; vv < 16; ++vv){
      int chn = h * 64 + g * 16 + vv;
      ob[(size_t)chn * N_] = acc[h][vv] + qb[h];
    }
  }
}

extern "C" void kernel_launch(void* const* d_in, const int* in_sizes, int n_in,
                              void* d_out, int out_size, void* d_ws, size_t ws_size,
                              hipStream_t stream){
  (void)in_sizes; (void)n_in; (void)out_size; (void)ws_size;
  const float* x  = (const float*)d_in[0];
  const float* Wq = (const float*)d_in[1];
  const float* Wk = (const float*)d_in[2];
  const float* Wv = (const float*)d_in[3];
  const float* gq = (const float*)d_in[4];
  const float* bq = (const float*)d_in[5];
  const float* gv = (const float*)d_in[6];
  const float* bv = (const float*)d_in[7];
  const float* pw = (const float*)d_in[8];
  const float* pb = (const float*)d_in[9];
  float* out = (float*)d_out;

  char* ws = (char*)d_ws;
  _Float16* Wcat = (_Float16*)ws;                           // 73,728 B
  float* P     = (float*)(ws + 131072);                     // 144*65536*4 = 37,748,736 B
  float* stats = (float*)(ws + 131072 + (size_t)M_ * NT_ * 4); // 256 floats
  float* kstat = stats + 256;                               // 512 floats
  float* lc    = kstat + 512;                               // 16*16*64 floats

  k_pack_w  <<<144, 256, 0, stream>>>(Wq, Wk, Wv, Wcat);
  k_proj    <<<1024, 256, 0, stream>>>(x, Wcat, P);
  k_bnstats <<<128, 256, 0, stream>>>(P, gq, bq, gv, bv, stats);
  k_softstats<<<256, 256, 0, stream>>>(P, kstat);
  k_lambda  <<<256, 256, 0, stream>>>(P, stats, kstat, lc);
  dim3 g4(4, 16, 16);
  k_final   <<<g4, 256, 0, stream>>>(P, stats, lc, pw, pb, out);
}

// Round 2
// 252.050 us; speedup vs baseline: 1.2123x; 1.2123x over previous
//
#include <hip/hip_runtime.h>

// LambdaLayer2D: B=16, C=256, H=W=64, K=16, HEADS=4, U=1, V=64, R=7
#define B_ 16
#define C_ 256
#define N_ 4096            // H*W
#define NT_ 65536          // B*N
#define M_ 144             // 64 q-rows + 16 k-rows + 64 v-rows
#define M2_ 464            // gemm2 rows: 196 s + 12 pad + 256 y_c
#define SROWS_ 196

typedef _Float16 f16x8 __attribute__((ext_vector_type(8)));
typedef _Float16 f16x2 __attribute__((ext_vector_type(2)));
typedef float    f32x4 __attribute__((ext_vector_type(4)));

__device__ __forceinline__ float waveSum(float v){
  #pragma unroll
  for (int off = 32; off > 0; off >>= 1) v += __shfl_xor(v, off, 64);
  return v;
}
__device__ __forceinline__ float waveMax(float v){
  #pragma unroll
  for (int off = 32; off > 0; off >>= 1) v = fmaxf(v, __shfl_xor(v, off, 64));
  return v;
}

// ---------------- K0: pack Wq|Wk|Wv -> fp16 [144][256] ----------------
__global__ void k_pack_w(const float* __restrict__ Wq, const float* __restrict__ Wk,
                         const float* __restrict__ Wv, _Float16* __restrict__ Wcat){
  int idx = blockIdx.x * 256 + threadIdx.x;   // 144*256 = 36864
  int row = idx >> 8, col = idx & 255;
  float v;
  if (row < 64)      v = Wq[row * 256 + col];
  else if (row < 80) v = Wk[(row - 64) * 256 + col];
  else               v = Wv[(row - 80) * 256 + col];
  Wcat[idx] = (_Float16)v;
}

// ---------------- K1: projection GEMM P[144][65536] = Wcat @ X -------
__global__ __launch_bounds__(256) void k_proj(const float* __restrict__ x,
                                              const _Float16* __restrict__ Wcat,
                                              float* __restrict__ P){
  const int lane = threadIdx.x & 63;
  const int wid  = threadIdx.x >> 6;
  const int tile = blockIdx.x * 4 + wid;   // 0..4095
  const int j0 = tile << 4;
  const int b  = j0 >> 12;
  const int n0 = j0 & 4095;
  const int cl = lane & 15;
  const int kg = lane >> 4;

  f32x4 acc[9];
  #pragma unroll
  for (int m = 0; m < 9; ++m){ acc[m][0]=0.f; acc[m][1]=0.f; acc[m][2]=0.f; acc[m][3]=0.f; }

  const float* xb = x + (size_t)b * C_ * N_ + n0 + cl;
  #pragma unroll
  for (int kk = 0; kk < 8; ++kk){
    const int kb = kk * 32 + kg * 8;
    f16x8 bfrag;
    #pragma unroll
    for (int jj = 0; jj < 8; ++jj) bfrag[jj] = (_Float16)xb[(size_t)(kb + jj) * N_];
    #pragma unroll
    for (int m = 0; m < 9; ++m){
      f16x8 afrag = *reinterpret_cast<const f16x8*>(Wcat + ((m * 16 + cl) << 8) + kb);
      acc[m] = __builtin_amdgcn_mfma_f32_16x16x32_f16(afrag, bfrag, acc[m], 0, 0, 0);
    }
  }
  float* Pw = P + j0 + cl;
  #pragma unroll
  for (int m = 0; m < 9; ++m){
    #pragma unroll
    for (int r = 0; r < 4; ++r){
      int o = m * 16 + kg * 4 + r;
      Pw[(size_t)o * NT_] = acc[m][r];
    }
  }
}

// ---------------- K2a: BN partial sums (128 ch x 8 slices) -----------
__global__ void k_bn1(const float* __restrict__ P, float* __restrict__ bnpart){
  const int ch = blockIdx.x >> 3, sl = blockIdx.x & 7;
  const int o = (ch < 64) ? ch : (80 + (ch - 64));
  const float* row = P + (size_t)o * NT_ + sl * 8192;
  float s = 0.f, ss = 0.f;
  for (int i = threadIdx.x; i < 8192; i += 256){ float v = row[i]; s += v; ss += v * v; }
  __shared__ float r0[4], r1[4];
  const int lane = threadIdx.x & 63, wid = threadIdx.x >> 6;
  s = waveSum(s); ss = waveSum(ss);
  if (lane == 0){ r0[wid] = s; r1[wid] = ss; }
  __syncthreads();
  if (threadIdx.x == 0){
    bnpart[blockIdx.x * 2]     = r0[0] + r0[1] + r0[2] + r0[3];
    bnpart[blockIdx.x * 2 + 1] = r1[0] + r1[1] + r1[2] + r1[3];
  }
}

// ---------------- K2b: finalize BN -> folded affine ------------------
// stats layout: [0:64) aq, [64:128) cq, [128:192) av, [192:256) cv
__global__ void k_bn2(const float* __restrict__ bnpart,
                      const float* __restrict__ gq, const float* __restrict__ bq,
                      const float* __restrict__ gv, const float* __restrict__ bv,
                      float* __restrict__ stats){
  int ch = threadIdx.x;            // 0..127
  if (ch >= 128) return;
  float s = 0.f, ss = 0.f;
  #pragma unroll
  for (int sl = 0; sl < 8; ++sl){ s += bnpart[(ch*8+sl)*2]; ss += bnpart[(ch*8+sl)*2+1]; }
  float mean = s * (1.f / NT_);
  float var  = ss * (1.f / NT_) - mean * mean;
  float rs = rsqrtf(var + 1e-5f);
  if (ch < 64){
    float a = rs * gq[ch];
    stats[ch] = a; stats[64 + ch] = bq[ch] - mean * a;
  } else {
    int v = ch - 64;
    float a = rs * gv[v];
    stats[128 + v] = a; stats[192 + v] = bv[v] - mean * a;
  }
}

// ---------------- K3: softmax row stats (max, 1/sumexp) --------------
__global__ void k_softstats(const float* __restrict__ P, float* __restrict__ kstat){
  const int bid = blockIdx.x;                   // b*16 + kc
  const int b = bid >> 4, kc = bid & 15;
  const float* row = P + (size_t)(64 + kc) * NT_ + b * N_;
  const int lane = threadIdx.x & 63, wid = threadIdx.x >> 6;
  __shared__ float sm[4], sb[4];
  float m = -1e30f;
  for (int i = threadIdx.x; i < N_; i += 256) m = fmaxf(m, row[i]);
  m = waveMax(m);
  if (lane == 0) sm[wid] = m;
  __syncthreads();
  float mg = fmaxf(fmaxf(sm[0], sm[1]), fmaxf(sm[2], sm[3]));
  float s = 0.f;
  for (int i = threadIdx.x; i < N_; i += 256) s += __expf(row[i] - mg);
  s = waveSum(s);
  if (lane == 0) sb[wid] = s;
  __syncthreads();
  if (threadIdx.x == 0){
    kstat[bid] = mg;
    kstat[256 + bid] = 1.f / (sb[0] + sb[1] + sb[2] + sb[3]);
  }
}

// ---------------- K4a: lambda_c partial sums -------------------------
__global__ __launch_bounds__(256) void k_lam1(const float* __restrict__ P,
                          const float* __restrict__ kstat,
                          float* __restrict__ lc_part){
  const int bid = blockIdx.x >> 2, sl = blockIdx.x & 3;   // bid = b*16+kc
  const int b = bid >> 4, kc = bid & 15;
  const int lane = threadIdx.x & 63, g = threadIdx.x >> 6;
  const float* krow = P + (size_t)(64 + kc) * NT_ + b * N_ + sl * 1024;
  const float km = kstat[bid], ki = kstat[256 + bid];
  const float* vb = P + (size_t)80 * NT_ + b * N_ + sl * 1024;
  float S[16];
  #pragma unroll
  for (int i = 0; i < 16; ++i) S[i] = 0.f;
  for (int it = 0; it < 16; ++it){
    int n = lane + it * 64;
    float sk = __expf(krow[n] - km) * ki;
    #pragma unroll
    for (int vv = 0; vv < 16; ++vv) S[vv] += sk * vb[(size_t)(g * 16 + vv) * NT_ + n];
  }
  #pragma unroll
  for (int vv = 0; vv < 16; ++vv){
    float r = waveSum(S[vv]);
    if (lane == 0) lc_part[(size_t)blockIdx.x * 64 + g * 16 + vv] = r;
  }
}

// ---------------- K4b: finalize lambda_c (+BN affine +pos_b) ---------
__global__ void k_lam2(const float* __restrict__ lc_part,
                       const float* __restrict__ stats,
                       const float* __restrict__ pos_b,
                       float* __restrict__ lcp){
  for (int o = threadIdx.x; o < 16384; o += 256){
    int bid = o >> 6, v = o & 63, kc = bid & 15;
    float s = 0.f;
    #pragma unroll
    for (int sl = 0; sl < 4; ++sl) s += lc_part[(size_t)(bid * 4 + sl) * 64 + v];
    lcp[(size_t)bid * 64 + v] = stats[128 + v] * s + stats[192 + v] + pos_b[kc];
  }
}

// ---------------- K5: build per-batch big weight [464][64] -----------
// rows 0..195: s rows (h,dy,dx); 196..207: zero; 208..463: y_c rows (h,v)
__global__ void k_makeW(const float* __restrict__ stats, const float* __restrict__ lcp,
                        const float* __restrict__ pos_w,
                        _Float16* __restrict__ Wbig, float* __restrict__ Bbig){
  const int b = blockIdx.x;
  for (int r = threadIdx.x; r < M2_; r += 256){
    float bias = 0.f;
    _Float16* wrow = Wbig + ((size_t)(b * M2_ + r) << 6);
    if (r < SROWS_){
      int h = r / 49, tap = r % 49;
      for (int c = 0; c < 64; ++c)
        wrow[c] = (_Float16)(((c >> 4) == h) ? stats[c] * pos_w[(c & 15) * 49 + tap] : 0.f);
      for (int k = 0; k < 16; ++k) bias += stats[64 + h * 16 + k] * pos_w[k * 49 + tap];
    } else if (r < 208){
      for (int c = 0; c < 64; ++c) wrow[c] = (_Float16)0.f;
    } else {
      int hv = r - 208, h = hv >> 6, v = hv & 63;
      for (int c = 0; c < 64; ++c)
        wrow[c] = (_Float16)(((c >> 4) == h) ? stats[c] * lcp[(size_t)(b * 16 + (c & 15)) * 64 + v] : 0.f);
      for (int k = 0; k < 16; ++k) bias += stats[64 + h * 16 + k] * lcp[(size_t)(b * 16 + k) * 64 + v];
    }
    Bbig[b * M2_ + r] = bias;
  }
}

// ---------------- K6: big GEMM: S rows -> S (f16), y_c rows -> out ---
__global__ __launch_bounds__(256) void k_gemm2(const float* __restrict__ P,
                        const _Float16* __restrict__ Wbig, const float* __restrict__ Bbig,
                        _Float16* __restrict__ Sg, float* __restrict__ out){
  const int lane = threadIdx.x & 63;
  const int wid  = threadIdx.x >> 6;
  const int tile = blockIdx.x * 4 + wid;   // 0..4095
  const int j0 = tile << 4;
  const int b  = j0 >> 12;
  const int n0 = j0 & 4095;
  const int cl = lane & 15;
  const int kg = lane >> 4;

  f32x4 acc[29];
  #pragma unroll
  for (int m = 0; m < 29; ++m){ acc[m][0]=0.f; acc[m][1]=0.f; acc[m][2]=0.f; acc[m][3]=0.f; }

  const float* qb = P + j0 + cl;                 // q rows 0..63
  const _Float16* Wb = Wbig + ((size_t)b * M2_ << 6);
  #pragma unroll
  for (int kk = 0; kk < 2; ++kk){
    const int kb = kk * 32 + kg * 8;
    f16x8 bfrag;
    #pragma unroll
    for (int jj = 0; jj < 8; ++jj) bfrag[jj] = (_Float16)qb[(size_t)(kb + jj) * NT_];
    #pragma unroll
    for (int m = 0; m < 29; ++m){
      f16x8 afrag = *reinterpret_cast<const f16x8*>(Wb + ((m * 16 + cl) << 6) + kb);
      acc[m] = __builtin_amdgcn_mfma_f32_16x16x32_f16(afrag, bfrag, acc[m], 0, 0, 0);
    }
  }
  const float* Bb = Bbig + b * M2_;
  #pragma unroll
  for (int m = 0; m < 29; ++m){
    #pragma unroll
    for (int r = 0; r < 4; ++r){
      int row = m * 16 + kg * 4 + r;
      float val = acc[m][r] + Bb[row];
      if (row < SROWS_)       Sg[(size_t)row * NT_ + j0 + cl] = (_Float16)val;
      else if (row >= 208)    out[((size_t)((b << 8) + (row - 208))) * N_ + n0 + cl] = val;
    }
  }
}

// ---------------- K7: banded rank-1: out += sum_tap s * vn_shift -----
__global__ __launch_bounds__(256) void k_band(const float* __restrict__ P,
                        const float* __restrict__ stats,
                        const _Float16* __restrict__ Sg,
                        float* __restrict__ out){
  __shared__ _Float16 vn_s[220][70];   // [pos=10x22][v pad 70]
  const int b  = blockIdx.z;
  const int x0 = blockIdx.x * 16;
  const int y0 = blockIdx.y * 4;
  const int tid = threadIdx.x;
  const float* Pv = P + (size_t)80 * NT_ + b * N_;

  for (int f = tid; f < 64 * 220; f += 256){
    int v = f / 220, pos = f - v * 220;
    int yy = pos / 22, xx = pos - yy * 22;
    int gy = y0 + yy - 3, gx = x0 + xx - 3;
    float val = 0.f;                               // 'SAME' zero padding
    if ((unsigned)gy < 64u && (unsigned)gx < 64u)
      val = Pv[(size_t)v * NT_ + gy * 64 + gx] * stats[128 + v] + stats[192 + v];
    vn_s[pos][v] = (_Float16)val;
  }
  __syncthreads();

  const int p = tid & 63, g = tid >> 6;
  const int py = p >> 4, px = p & 15;
  const int pix = (y0 + py) * 64 + x0 + px;
  const _Float16* Sn = Sg + (size_t)b * N_ + pix;

  f16x2 acc2[4][8];
  #pragma unroll
  for (int h = 0; h < 4; ++h)
    #pragma unroll
    for (int vp = 0; vp < 8; ++vp){ acc2[h][vp][0] = (_Float16)0.f; acc2[h][vp][1] = (_Float16)0.f; }

  for (int dy = 0; dy < 7; ++dy){
    f16x2 ss[4][7];
    #pragma unroll
    for (int h = 0; h < 4; ++h){
      #pragma unroll
      for (int dx = 0; dx < 7; ++dx){
        _Float16 sv = Sn[(size_t)((h * 7 + dy) * 7 + dx) * NT_];
        ss[h][dx][0] = sv; ss[h][dx][1] = sv;
      }
    }
    #pragma unroll
    for (int dx = 0; dx < 7; ++dx){
      const _Float16* vrow = &vn_s[(py + dy) * 22 + px + dx][g * 16];
      #pragma unroll
      for (int vp = 0; vp < 8; ++vp){
        f16x2 vn2 = *reinterpret_cast<const f16x2*>(vrow + 2 * vp);
        acc2[0][vp] = ss[0][dx] * vn2 + acc2[0][vp];
        acc2[1][vp] = ss[1][dx] * vn2 + acc2[1][vp];
        acc2[2][vp] = ss[2][dx] * vn2 + acc2[2][vp];
        acc2[3][vp] = ss[3][dx] * vn2 + acc2[3][vp];
      }
    }
  }

  float* ob = out + (size_t)b * 256 * N_ + pix;
  #pragma unroll
  for (int h = 0; h < 4; ++h){
    #pragma unroll
    for (int vp = 0; vp < 8; ++vp){
      int chn = h * 64 + g * 16 + 2 * vp;
      ob[(size_t)chn * N_]       += (float)acc2[h][vp][0];
      ob[(size_t)(chn + 1) * N_] += (float)acc2[h][vp][1];
    }
  }
}

extern "C" void kernel_launch(void* const* d_in, const int* in_sizes, int n_in,
                              void* d_out, int out_size, void* d_ws, size_t ws_size,
                              hipStream_t stream){
  (void)in_sizes; (void)n_in; (void)out_size; (void)ws_size;
  const float* x  = (const float*)d_in[0];
  const float* Wq = (const float*)d_in[1];
  const float* Wk = (const float*)d_in[2];
  const float* Wv = (const float*)d_in[3];
  const float* gq = (const float*)d_in[4];
  const float* bq = (const float*)d_in[5];
  const float* gv = (const float*)d_in[6];
  const float* bv = (const float*)d_in[7];
  const float* pw = (const float*)d_in[8];
  const float* pb = (const float*)d_in[9];
  float* out = (float*)d_out;

  char* ws = (char*)d_ws;
  _Float16* Wcat = (_Float16*)ws;                               // 73,728 B
  float*    P    = (float*)(ws + 131072);                       // 37,748,736 B
  size_t off = 131072 + (size_t)M_ * NT_ * 4;
  _Float16* Sg   = (_Float16*)(ws + off);  off += (size_t)SROWS_ * NT_ * 2;   // 25,690,112
  _Float16* Wbig = (_Float16*)(ws + off);  off += (size_t)B_ * M2_ * 64 * 2;  // 950,272
  float*    Bbig = (float*)(ws + off);     off += (size_t)B_ * M2_ * 4;       // 29,696
  float*    stats   = (float*)(ws + off);  off += 256 * 4;
  float*    kstat   = (float*)(ws + off);  off += 512 * 4;
  float*    lcp     = (float*)(ws + off);  off += 256 * 64 * 4;
  float*    lc_part = (float*)(ws + off);  off += 1024 * 64 * 4;
  float*    bnpart  = (float*)(ws + off);  off += 1024 * 2 * 4;

  k_pack_w   <<<144, 256, 0, stream>>>(Wq, Wk, Wv, Wcat);
  k_proj     <<<1024, 256, 0, stream>>>(x, Wcat, P);
  k_bn1      <<<1024, 256, 0, stream>>>(P, bnpart);
  k_bn2      <<<1, 128, 0, stream>>>(bnpart, gq, bq, gv, bv, stats);
  k_softstats<<<256, 256, 0, stream>>>(P, kstat);
  k_lam1     <<<1024, 256, 0, stream>>>(P, kstat, lc_part);
  k_lam2     <<<1, 256, 0, stream>>>(lc_part, stats, pb, lcp);
  k_makeW    <<<16, 256, 0, stream>>>(stats, lcp, pw, Wbig, Bbig);
  k_gemm2    <<<1024, 256, 0, stream>>>(P, Wbig, Bbig, Sg, out);
  dim3 g7(4, 16, 16);
  k_band     <<<g7, 256, 0, stream>>>(P, stats, Sg, out);
}

// Round 3
// 248.722 us; speedup vs baseline: 1.2285x; 1.0134x over previous
//
#include <hip/hip_runtime.h>

// LambdaLayer2D: B=16, C=256, H=W=64, K=16, HEADS=4, U=1, V=64, R=7
#define B_ 16
#define C_ 256
#define N_ 4096            // H*W
#define NT_ 65536          // B*N
#define M_ 144             // 64 q-rows + 16 k-rows + 64 v-rows
#define M2_ 464            // fused rows: 196 s + 12 pad + 256 y_c
#define SROWS_ 196
#define VNW 72             // vn LDS stride (f16), multiple of 4 -> 8B aligned f16x4
#define SST 18             // s_s LDS stride (f16)

typedef _Float16 f16x8 __attribute__((ext_vector_type(8)));
typedef _Float16 f16x4 __attribute__((ext_vector_type(4)));
typedef _Float16 f16x2 __attribute__((ext_vector_type(2)));
typedef float    f32x4 __attribute__((ext_vector_type(4)));

__device__ __forceinline__ float waveSum(float v){
  #pragma unroll
  for (int off = 32; off > 0; off >>= 1) v += __shfl_xor(v, off, 64);
  return v;
}
__device__ __forceinline__ float waveMax(float v){
  #pragma unroll
  for (int off = 32; off > 0; off >>= 1) v = fmaxf(v, __shfl_xor(v, off, 64));
  return v;
}

// ---------------- K0: pack Wq|Wk|Wv -> fp16 [144][256] ----------------
__global__ void k_pack_w(const float* __restrict__ Wq, const float* __restrict__ Wk,
                         const float* __restrict__ Wv, _Float16* __restrict__ Wcat){
  int idx = blockIdx.x * 256 + threadIdx.x;   // 144*256 = 36864
  int row = idx >> 8, col = idx & 255;
  float v;
  if (row < 64)      v = Wq[row * 256 + col];
  else if (row < 80) v = Wk[(row - 64) * 256 + col];
  else               v = Wv[(row - 80) * 256 + col];
  Wcat[idx] = (_Float16)v;
}

// ---------------- K1: projection GEMM P[144][65536] = Wcat @ X -------
__global__ __launch_bounds__(256) void k_proj(const float* __restrict__ x,
                                              const _Float16* __restrict__ Wcat,
                                              float* __restrict__ P){
  const int lane = threadIdx.x & 63;
  const int wid  = threadIdx.x >> 6;
  const int tile = blockIdx.x * 4 + wid;   // 0..4095
  const int j0 = tile << 4;
  const int b  = j0 >> 12;
  const int n0 = j0 & 4095;
  const int cl = lane & 15;
  const int kg = lane >> 4;

  f32x4 acc[9];
  #pragma unroll
  for (int m = 0; m < 9; ++m){ acc[m][0]=0.f; acc[m][1]=0.f; acc[m][2]=0.f; acc[m][3]=0.f; }

  const float* xb = x + (size_t)b * C_ * N_ + n0 + cl;
  #pragma unroll
  for (int kk = 0; kk < 8; ++kk){
    const int kb = kk * 32 + kg * 8;
    f16x8 bfrag;
    #pragma unroll
    for (int jj = 0; jj < 8; ++jj) bfrag[jj] = (_Float16)xb[(size_t)(kb + jj) * N_];
    #pragma unroll
    for (int m = 0; m < 9; ++m){
      f16x8 afrag = *reinterpret_cast<const f16x8*>(Wcat + ((m * 16 + cl) << 8) + kb);
      acc[m] = __builtin_amdgcn_mfma_f32_16x16x32_f16(afrag, bfrag, acc[m], 0, 0, 0);
    }
  }
  float* Pw = P + j0 + cl;
  #pragma unroll
  for (int m = 0; m < 9; ++m){
    #pragma unroll
    for (int r = 0; r < 4; ++r){
      int o = m * 16 + kg * 4 + r;
      Pw[(size_t)o * NT_] = acc[m][r];
    }
  }
}

// ---------------- K2a: BN partial sums (128 ch x 8 slices) -----------
__global__ void k_bn1(const float* __restrict__ P, float* __restrict__ bnpart){
  const int ch = blockIdx.x >> 3, sl = blockIdx.x & 7;
  const int o = (ch < 64) ? ch : (80 + (ch - 64));
  const float* row = P + (size_t)o * NT_ + sl * 8192;
  float s = 0.f, ss = 0.f;
  for (int i = threadIdx.x; i < 8192; i += 256){ float v = row[i]; s += v; ss += v * v; }
  __shared__ float r0[4], r1[4];
  const int lane = threadIdx.x & 63, wid = threadIdx.x >> 6;
  s = waveSum(s); ss = waveSum(ss);
  if (lane == 0){ r0[wid] = s; r1[wid] = ss; }
  __syncthreads();
  if (threadIdx.x == 0){
    bnpart[blockIdx.x * 2]     = r0[0] + r0[1] + r0[2] + r0[3];
    bnpart[blockIdx.x * 2 + 1] = r1[0] + r1[1] + r1[2] + r1[3];
  }
}

// ---------------- K2b: finalize BN -> folded affine ------------------
// stats layout: [0:64) aq, [64:128) cq, [128:192) av, [192:256) cv
__global__ void k_bn2(const float* __restrict__ bnpart,
                      const float* __restrict__ gq, const float* __restrict__ bq,
                      const float* __restrict__ gv, const float* __restrict__ bv,
                      float* __restrict__ stats){
  int ch = threadIdx.x;            // 0..127
  if (ch >= 128) return;
  float s = 0.f, ss = 0.f;
  #pragma unroll
  for (int sl = 0; sl < 8; ++sl){ s += bnpart[(ch*8+sl)*2]; ss += bnpart[(ch*8+sl)*2+1]; }
  float mean = s * (1.f / NT_);
  float var  = ss * (1.f / NT_) - mean * mean;
  float rs = rsqrtf(var + 1e-5f);
  if (ch < 64){
    float a = rs * gq[ch];
    stats[ch] = a; stats[64 + ch] = bq[ch] - mean * a;
  } else {
    int v = ch - 64;
    float a = rs * gv[v];
    stats[128 + v] = a; stats[192 + v] = bv[v] - mean * a;
  }
}

// ---------------- K3: softmax row stats (max, 1/sumexp) --------------
__global__ void k_softstats(const float* __restrict__ P, float* __restrict__ kstat){
  const int bid = blockIdx.x;                   // b*16 + kc
  const int b = bid >> 4, kc = bid & 15;
  const float* row = P + (size_t)(64 + kc) * NT_ + b * N_;
  const int lane = threadIdx.x & 63, wid = threadIdx.x >> 6;
  __shared__ float sm[4], sb[4];
  float m = -1e30f;
  for (int i = threadIdx.x; i < N_; i += 256) m = fmaxf(m, row[i]);
  m = waveMax(m);
  if (lane == 0) sm[wid] = m;
  __syncthreads();
  float mg = fmaxf(fmaxf(sm[0], sm[1]), fmaxf(sm[2], sm[3]));
  float s = 0.f;
  for (int i = threadIdx.x; i < N_; i += 256) s += __expf(row[i] - mg);
  s = waveSum(s);
  if (lane == 0) sb[wid] = s;
  __syncthreads();
  if (threadIdx.x == 0){
    kstat[bid] = mg;
    kstat[256 + bid] = 1.f / (sb[0] + sb[1] + sb[2] + sb[3]);
  }
}

// ---------------- K4a: lambda_c partial sums -------------------------
__global__ __launch_bounds__(256) void k_lam1(const float* __restrict__ P,
                          const float* __restrict__ kstat,
                          float* __restrict__ lc_part){
  const int bid = blockIdx.x >> 2, sl = blockIdx.x & 3;   // bid = b*16+kc
  const int b = bid >> 4, kc = bid & 15;
  const int lane = threadIdx.x & 63, g = threadIdx.x >> 6;
  const float* krow = P + (size_t)(64 + kc) * NT_ + b * N_ + sl * 1024;
  const float km = kstat[bid], ki = kstat[256 + bid];
  const float* vb = P + (size_t)80 * NT_ + b * N_ + sl * 1024;
  float S[16];
  #pragma unroll
  for (int i = 0; i < 16; ++i) S[i] = 0.f;
  for (int it = 0; it < 16; ++it){
    int n = lane + it * 64;
    float sk = __expf(krow[n] - km) * ki;
    #pragma unroll
    for (int vv = 0; vv < 16; ++vv) S[vv] += sk * vb[(size_t)(g * 16 + vv) * NT_ + n];
  }
  #pragma unroll
  for (int vv = 0; vv < 16; ++vv){
    float r = waveSum(S[vv]);
    if (lane == 0) lc_part[(size_t)blockIdx.x * 64 + g * 16 + vv] = r;
  }
}

// ---------------- K4b: finalize lambda_c (+BN affine +pos_b) ---------
__global__ void k_lam2(const float* __restrict__ lc_part,
                       const float* __restrict__ stats,
                       const float* __restrict__ pos_b,
                       float* __restrict__ lcp){
  for (int o = threadIdx.x; o < 16384; o += 256){
    int bid = o >> 6, v = o & 63, kc = bid & 15;
    float s = 0.f;
    #pragma unroll
    for (int sl = 0; sl < 4; ++sl) s += lc_part[(size_t)(bid * 4 + sl) * 64 + v];
    lcp[(size_t)bid * 64 + v] = stats[128 + v] * s + stats[192 + v] + pos_b[kc];
  }
}

// ---------------- K5: build per-batch big weight [464][64] -----------
// rows 0..195: s rows (h,dy,dx); 196..207: zero; 208..463: y_c rows (h,v)
__global__ void k_makeW(const float* __restrict__ stats, const float* __restrict__ lcp,
                        const float* __restrict__ pos_w,
                        _Float16* __restrict__ Wbig, float* __restrict__ Bbig){
  const int b = blockIdx.x;
  for (int r = threadIdx.x; r < M2_; r += 256){
    float bias = 0.f;
    _Float16* wrow = Wbig + ((size_t)(b * M2_ + r) << 6);
    if (r < SROWS_){
      int h = r / 49, tap = r % 49;
      for (int c = 0; c < 64; ++c)
        wrow[c] = (_Float16)(((c >> 4) == h) ? stats[c] * pos_w[(c & 15) * 49 + tap] : 0.f);
      for (int k = 0; k < 16; ++k) bias += stats[64 + h * 16 + k] * pos_w[k * 49 + tap];
    } else if (r < 208){
      for (int c = 0; c < 64; ++c) wrow[c] = (_Float16)0.f;
    } else {
      int hv = r - 208, h = hv >> 6, v = hv & 63;
      for (int c = 0; c < 64; ++c)
        wrow[c] = (_Float16)(((c >> 4) == h) ? stats[c] * lcp[(size_t)(b * 16 + (c & 15)) * 64 + v] : 0.f);
      for (int k = 0; k < 16; ++k) bias += stats[64 + h * 16 + k] * lcp[(size_t)(b * 16 + k) * 64 + v];
    }
    Bbig[b * M2_ + r] = bias;
  }
}

// ---------------- K6: fused S-GEMM + y_c-GEMM + banded conv ----------
// Block: 16x4 pixel tile, 4 waves (wave wid = pixel row y0+wid).
// Per wave: MFMA over q[64] x Wbig[464] for its 16 pixels. S rows ->
// per-wave LDS tile; y_c rows stay in acc. Band phase: thread (cl,kg)
// owns pixel cl and v-set {vhi*16+kg*4+r}; packed f16x2 FMA over 49 taps.
// Single write of out (no RMW).
__global__ __launch_bounds__(256) void k_fused(const float* __restrict__ P,
                        const float* __restrict__ stats,
                        const _Float16* __restrict__ Wbig,
                        const float* __restrict__ Bbig,
                        float* __restrict__ out){
  __shared__ _Float16 vn_s[220][VNW];       // halo 10x22, normalized v (f16)
  __shared__ _Float16 s_s[4][SROWS_][SST];  // per-wave S tile [row][pix]

  const int b  = blockIdx.z;
  const int x0 = blockIdx.x * 16;
  const int y0 = blockIdx.y * 4;
  const int tid = threadIdx.x;
  const int lane = tid & 63, wid = tid >> 6;
  const int cl = lane & 15, kg = lane >> 4;

  // ---- MFMA phase: 29 row-tiles for this wave's 16 pixels ----
  const int pix0 = (y0 + wid) * 64 + x0;
  const float* qb = P + (size_t)b * N_ + pix0 + cl;
  const _Float16* Wb = Wbig + ((size_t)b * M2_ << 6);
  const float* Bb = Bbig + b * M2_;

  f32x4 acc[29];
  #pragma unroll
  for (int m = 0; m < 29; ++m){ acc[m][0]=0.f; acc[m][1]=0.f; acc[m][2]=0.f; acc[m][3]=0.f; }

  #pragma unroll
  for (int kk = 0; kk < 2; ++kk){
    const int kb = kk * 32 + kg * 8;
    f16x8 bfrag;
    #pragma unroll
    for (int jj = 0; jj < 8; ++jj) bfrag[jj] = (_Float16)qb[(size_t)(kb + jj) * NT_];
    #pragma unroll
    for (int m = 0; m < 29; ++m){
      f16x8 afrag = *reinterpret_cast<const f16x8*>(Wb + ((m * 16 + cl) << 6) + kb);
      acc[m] = __builtin_amdgcn_mfma_f32_16x16x32_f16(afrag, bfrag, acc[m], 0, 0, 0);
    }
  }

  // S rows (+bias) -> per-wave LDS
  #pragma unroll
  for (int m = 0; m < 13; ++m){
    #pragma unroll
    for (int r = 0; r < 4; ++r){
      int row = m * 16 + kg * 4 + r;
      if (row < SROWS_) s_s[wid][row][cl] = (_Float16)(acc[m][r] + Bb[row]);
    }
  }

  // ---- vn halo staging (normalized v, f16) ----
  {
    const int v = tid >> 2, l4 = tid & 3;
    const float a = stats[128 + v], c = stats[192 + v];
    const float* Pv = P + (size_t)(80 + v) * NT_ + b * N_;
    for (int yy = 0; yy < 10; ++yy){
      int gy = y0 + yy - 3;
      bool yok = (unsigned)gy < 64u;
      const float* prow = Pv + gy * 64;
      for (int xx = l4; xx < 22; xx += 4){
        int gx = x0 + xx - 3;
        float val = 0.f;
        if (yok && (unsigned)gx < 64u) val = prow[gx] * a + c;
        vn_s[yy * 22 + xx][v] = (_Float16)val;
      }
    }
  }
  __syncthreads();

  // ---- band phase: packed f16x2 rank-1 over 49 taps ----
  f16x2 accB[4][4][2];   // [h][vhi][pair], pair covers r = 2*pair..2*pair+1
  #pragma unroll
  for (int h = 0; h < 4; ++h)
    #pragma unroll
    for (int vhi = 0; vhi < 4; ++vhi){
      accB[h][vhi][0][0]=(_Float16)0.f; accB[h][vhi][0][1]=(_Float16)0.f;
      accB[h][vhi][1][0]=(_Float16)0.f; accB[h][vhi][1][1]=(_Float16)0.f;
    }

  const _Float16* sb0 = &s_s[wid][0][cl];
  for (int dy = 0; dy < 7; ++dy){
    const _Float16* vrow = &vn_s[(wid + dy) * 22 + cl][kg * 4];
    #pragma unroll
    for (int dx = 0; dx < 7; ++dx){
      const int tap = dy * 7 + dx;
      f16x2 sh[4];
      #pragma unroll
      for (int h = 0; h < 4; ++h){
        _Float16 sv = sb0[(h * 49 + tap) * SST];
        sh[h][0] = sv; sh[h][1] = sv;
      }
      const _Float16* vp = vrow + dx * VNW;
      #pragma unroll
      for (int vhi = 0; vhi < 4; ++vhi){
        f16x4 v4 = *reinterpret_cast<const f16x4*>(vp + vhi * 16);
        f16x2 vlo; vlo[0] = v4[0]; vlo[1] = v4[1];
        f16x2 vhi2; vhi2[0] = v4[2]; vhi2[1] = v4[3];
        #pragma unroll
        for (int h = 0; h < 4; ++h){
          accB[h][vhi][0] = sh[h] * vlo  + accB[h][vhi][0];
          accB[h][vhi][1] = sh[h] * vhi2 + accB[h][vhi][1];
        }
      }
    }
  }

  // ---- merge y_c (MFMA acc) + band + bias, single store ----
  float* ob = out + ((size_t)b * 256) * N_ + pix0 + cl;
  #pragma unroll
  for (int h = 0; h < 4; ++h){
    #pragma unroll
    for (int vhi = 0; vhi < 4; ++vhi){
      const int m = 13 + h * 4 + vhi;
      #pragma unroll
      for (int r = 0; r < 4; ++r){
        int ch = h * 64 + vhi * 16 + kg * 4 + r;
        float band = (float)accB[h][vhi][r >> 1][r & 1];
        ob[(size_t)ch * N_] = acc[m][r] + band + Bb[208 + ch];
      }
    }
  }
}

extern "C" void kernel_launch(void* const* d_in, const int* in_sizes, int n_in,
                              void* d_out, int out_size, void* d_ws, size_t ws_size,
                              hipStream_t stream){
  (void)in_sizes; (void)n_in; (void)out_size; (void)ws_size;
  const float* x  = (const float*)d_in[0];
  const float* Wq = (const float*)d_in[1];
  const float* Wk = (const float*)d_in[2];
  const float* Wv = (const float*)d_in[3];
  const float* gq = (const float*)d_in[4];
  const float* bq = (const float*)d_in[5];
  const float* gv = (const float*)d_in[6];
  const float* bv = (const float*)d_in[7];
  const float* pw = (const float*)d_in[8];
  const float* pb = (const float*)d_in[9];
  float* out = (float*)d_out;

  char* ws = (char*)d_ws;
  _Float16* Wcat = (_Float16*)ws;                               // 73,728 B
  float*    P    = (float*)(ws + 131072);                       // 37,748,736 B
  size_t off = 131072 + (size_t)M_ * NT_ * 4;
  _Float16* Wbig = (_Float16*)(ws + off);  off += (size_t)B_ * M2_ * 64 * 2;  // 950,272
  float*    Bbig = (float*)(ws + off);     off += (size_t)B_ * M2_ * 4;       // 29,696
  float*    stats   = (float*)(ws + off);  off += 256 * 4;
  float*    kstat   = (float*)(ws + off);  off += 512 * 4;
  float*    lcp     = (float*)(ws + off);  off += 256 * 64 * 4;
  float*    lc_part = (float*)(ws + off);  off += 1024 * 64 * 4;
  float*    bnpart  = (float*)(ws + off);  off += 1024 * 2 * 4;

  k_pack_w   <<<144, 256, 0, stream>>>(Wq, Wk, Wv, Wcat);
  k_proj     <<<1024, 256, 0, stream>>>(x, Wcat, P);
  k_bn1      <<<1024, 256, 0, stream>>>(P, bnpart);
  k_bn2      <<<1, 128, 0, stream>>>(bnpart, gq, bq, gv, bv, stats);
  k_softstats<<<256, 256, 0, stream>>>(P, kstat);
  k_lam1     <<<1024, 256, 0, stream>>>(P, kstat, lc_part);
  k_lam2     <<<1, 256, 0, stream>>>(lc_part, stats, pb, lcp);
  k_makeW    <<<16, 256, 0, stream>>>(stats, lcp, pw, Wbig, Bbig);
  dim3 g6(4, 16, 16);
  k_fused    <<<g6, 256, 0, stream>>>(P, stats, Wbig, Bbig, out);
}

// Round 4
// 196.801 us; speedup vs baseline: 1.5526x; 1.2638x over previous
//
#include <hip/hip_runtime.h>

// LambdaLayer2D: B=16, C=256, H=W=64, K=16, HEADS=4, U=1, V=64, R=7
#define B_ 16
#define C_ 256
#define N_ 4096            // H*W
#define NT_ 65536          // B*N
#define M_ 144             // 64 q-rows + 16 k-rows + 64 v-rows
#define M2_ 464            // fused rows: 196 s + 4 ssum + 8 pad + 256 y_c
#define SROWS_ 196

typedef _Float16 f16x8 __attribute__((ext_vector_type(8)));
typedef _Float16 f16x4 __attribute__((ext_vector_type(4)));
typedef _Float16 f16x2 __attribute__((ext_vector_type(2)));
typedef float    f32x4 __attribute__((ext_vector_type(4)));

__device__ __forceinline__ float waveSum(float v){
  #pragma unroll
  for (int off = 32; off > 0; off >>= 1) v += __shfl_xor(v, off, 64);
  return v;
}
__device__ __forceinline__ float waveMax(float v){
  #pragma unroll
  for (int off = 32; off > 0; off >>= 1) v = fmaxf(v, __shfl_xor(v, off, 64));
  return v;
}

// ---------------- K0: pack Wq|Wk|Wv -> fp16 [144][256] ----------------
__global__ void k_pack_w(const float* __restrict__ Wq, const float* __restrict__ Wk,
                         const float* __restrict__ Wv, _Float16* __restrict__ Wcat){
  int idx = blockIdx.x * 256 + threadIdx.x;   // 144*256 = 36864
  int row = idx >> 8, col = idx & 255;
  float v;
  if (row < 64)      v = Wq[row * 256 + col];
  else if (row < 80) v = Wk[(row - 64) * 256 + col];
  else               v = Wv[(row - 80) * 256 + col];
  Wcat[idx] = (_Float16)v;
}

// ---------------- K1: projection GEMM P[144][65536] = Wcat @ X -------
// Also emits pixel-major f16 copies of raw q (rows 0..63) and raw v
// (rows 80..143): q16[n][64], v16[n][64].
__global__ __launch_bounds__(256) void k_proj(const float* __restrict__ x,
                                              const _Float16* __restrict__ Wcat,
                                              float* __restrict__ P,
                                              _Float16* __restrict__ q16,
                                              _Float16* __restrict__ v16){
  const int lane = threadIdx.x & 63;
  const int wid  = threadIdx.x >> 6;
  const int tile = blockIdx.x * 4 + wid;   // 0..4095
  const int j0 = tile << 4;
  const int b  = j0 >> 12;
  const int n0 = j0 & 4095;
  const int cl = lane & 15;
  const int kg = lane >> 4;

  f32x4 acc[9];
  #pragma unroll
  for (int m = 0; m < 9; ++m){ acc[m][0]=0.f; acc[m][1]=0.f; acc[m][2]=0.f; acc[m][3]=0.f; }

  const float* xb = x + (size_t)b * C_ * N_ + n0 + cl;
  #pragma unroll
  for (int kk = 0; kk < 8; ++kk){
    const int kb = kk * 32 + kg * 8;
    f16x8 bfrag;
    #pragma unroll
    for (int jj = 0; jj < 8; ++jj) bfrag[jj] = (_Float16)xb[(size_t)(kb + jj) * N_];
    #pragma unroll
    for (int m = 0; m < 9; ++m){
      f16x8 afrag = *reinterpret_cast<const f16x8*>(Wcat + ((m * 16 + cl) << 8) + kb);
      acc[m] = __builtin_amdgcn_mfma_f32_16x16x32_f16(afrag, bfrag, acc[m], 0, 0, 0);
    }
  }
  float* Pw = P + j0 + cl;
  #pragma unroll
  for (int m = 0; m < 9; ++m){
    #pragma unroll
    for (int r = 0; r < 4; ++r){
      int o = m * 16 + kg * 4 + r;
      Pw[(size_t)o * NT_] = acc[m][r];
    }
  }
  // pixel-major f16 q/v
  const size_t prow = ((size_t)(j0 + cl)) << 6;
  #pragma unroll
  for (int m = 0; m < 4; ++m){
    f16x4 h4;
    #pragma unroll
    for (int r = 0; r < 4; ++r) h4[r] = (_Float16)acc[m][r];
    *reinterpret_cast<f16x4*>(q16 + prow + m * 16 + kg * 4) = h4;
  }
  #pragma unroll
  for (int m = 5; m < 9; ++m){
    f16x4 h4;
    #pragma unroll
    for (int r = 0; r < 4; ++r) h4[r] = (_Float16)acc[m][r];
    *reinterpret_cast<f16x4*>(v16 + prow + (m - 5) * 16 + kg * 4) = h4;
  }
}

// ---------------- K2a: BN partial sums (128 ch x 8 slices) -----------
__global__ void k_bn1(const float* __restrict__ P, float* __restrict__ bnpart){
  const int ch = blockIdx.x >> 3, sl = blockIdx.x & 7;
  const int o = (ch < 64) ? ch : (80 + (ch - 64));
  const float4* row = (const float4*)(P + (size_t)o * NT_ + sl * 8192);
  float s = 0.f, ss = 0.f;
  for (int i = threadIdx.x; i < 2048; i += 256){
    float4 v = row[i];
    s  += v.x + v.y + v.z + v.w;
    ss += v.x*v.x + v.y*v.y + v.z*v.z + v.w*v.w;
  }
  __shared__ float r0[4], r1[4];
  const int lane = threadIdx.x & 63, wid = threadIdx.x >> 6;
  s = waveSum(s); ss = waveSum(ss);
  if (lane == 0){ r0[wid] = s; r1[wid] = ss; }
  __syncthreads();
  if (threadIdx.x == 0){
    bnpart[blockIdx.x * 2]     = r0[0] + r0[1] + r0[2] + r0[3];
    bnpart[blockIdx.x * 2 + 1] = r1[0] + r1[1] + r1[2] + r1[3];
  }
}

// ---------------- K2b: finalize BN -> folded affine ------------------
// stats layout: [0:64) aq, [64:128) cq, [128:192) av, [192:256) cv
__global__ void k_bn2(const float* __restrict__ bnpart,
                      const float* __restrict__ gq, const float* __restrict__ bq,
                      const float* __restrict__ gv, const float* __restrict__ bv,
                      float* __restrict__ stats){
  int ch = threadIdx.x;            // 0..127
  if (ch >= 128) return;
  float s = 0.f, ss = 0.f;
  #pragma unroll
  for (int sl = 0; sl < 8; ++sl){ s += bnpart[(ch*8+sl)*2]; ss += bnpart[(ch*8+sl)*2+1]; }
  float mean = s * (1.f / NT_);
  float var  = ss * (1.f / NT_) - mean * mean;
  float rs = rsqrtf(var + 1e-5f);
  if (ch < 64){
    float a = rs * gq[ch];
    stats[ch] = a; stats[64 + ch] = bq[ch] - mean * a;
  } else {
    int v = ch - 64;
    float a = rs * gv[v];
    stats[128 + v] = a; stats[192 + v] = bv[v] - mean * a;
  }
}

// ---------------- K3: softmax row stats (max, 1/sumexp) --------------
__global__ void k_softstats(const float* __restrict__ P, float* __restrict__ kstat){
  const int bid = blockIdx.x;                   // b*16 + kc
  const int b = bid >> 4, kc = bid & 15;
  const float* row = P + (size_t)(64 + kc) * NT_ + b * N_;
  const int lane = threadIdx.x & 63, wid = threadIdx.x >> 6;
  __shared__ float sm[4], sb[4];
  float m = -1e30f;
  for (int i = threadIdx.x; i < N_; i += 256) m = fmaxf(m, row[i]);
  m = waveMax(m);
  if (lane == 0) sm[wid] = m;
  __syncthreads();
  float mg = fmaxf(fmaxf(sm[0], sm[1]), fmaxf(sm[2], sm[3]));
  float s = 0.f;
  for (int i = threadIdx.x; i < N_; i += 256) s += __expf(row[i] - mg);
  s = waveSum(s);
  if (lane == 0) sb[wid] = s;
  __syncthreads();
  if (threadIdx.x == 0){
    kstat[bid] = mg;
    kstat[256 + bid] = 1.f / (sb[0] + sb[1] + sb[2] + sb[3]);
  }
}

// ---------------- K4a: lambda_c partial sums -------------------------
__global__ __launch_bounds__(256) void k_lam1(const float* __restrict__ P,
                          const float* __restrict__ kstat,
                          float* __restrict__ lc_part){
  const int bid = blockIdx.x >> 2, sl = blockIdx.x & 3;   // bid = b*16+kc
  const int b = bid >> 4, kc = bid & 15;
  const int lane = threadIdx.x & 63, g = threadIdx.x >> 6;
  const float* krow = P + (size_t)(64 + kc) * NT_ + b * N_ + sl * 1024;
  const float km = kstat[bid], ki = kstat[256 + bid];
  const float* vb = P + (size_t)80 * NT_ + b * N_ + sl * 1024;
  float S[16];
  #pragma unroll
  for (int i = 0; i < 16; ++i) S[i] = 0.f;
  for (int it = 0; it < 16; ++it){
    int n = lane + it * 64;
    float sk = __expf(krow[n] - km) * ki;
    #pragma unroll
    for (int vv = 0; vv < 16; ++vv) S[vv] += sk * vb[(size_t)(g * 16 + vv) * NT_ + n];
  }
  #pragma unroll
  for (int vv = 0; vv < 16; ++vv){
    float r = waveSum(S[vv]);
    if (lane == 0) lc_part[(size_t)blockIdx.x * 64 + g * 16 + vv] = r;
  }
}

// ---------------- K4b: finalize lambda_c (+BN affine +pos_b) ---------
__global__ void k_lam2(const float* __restrict__ lc_part,
                       const float* __restrict__ stats,
                       const float* __restrict__ pos_b,
                       float* __restrict__ lcp){
  for (int o = threadIdx.x; o < 16384; o += 256){
    int bid = o >> 6, v = o & 63, kc = bid & 15;
    float s = 0.f;
    #pragma unroll
    for (int sl = 0; sl < 4; ++sl) s += lc_part[(size_t)(bid * 4 + sl) * 64 + v];
    lcp[(size_t)bid * 64 + v] = stats[128 + v] * s + stats[192 + v] + pos_b[kc];
  }
}

// ---------------- K5: build per-batch big weight [464][64] -----------
// rows 0..195: s rows (h,tap); 196..199: ssum rows (h); 200..207: zero;
// 208..463: y_c rows (h, permuted v)
__global__ void k_makeW(const float* __restrict__ stats, const float* __restrict__ lcp,
                        const float* __restrict__ pos_w,
                        _Float16* __restrict__ Wbig, float* __restrict__ Bbig){
  const int b = blockIdx.x;
  for (int r = threadIdx.x; r < M2_; r += 256){
    float bias = 0.f;
    _Float16* wrow = Wbig + ((size_t)(b * M2_ + r) << 6);
    if (r < SROWS_){
      int h = r / 49, tap = r % 49;
      for (int c = 0; c < 64; ++c)
        wrow[c] = (_Float16)(((c >> 4) == h) ? stats[c] * pos_w[(c & 15) * 49 + tap] : 0.f);
      for (int k = 0; k < 16; ++k) bias += stats[64 + h * 16 + k] * pos_w[k * 49 + tap];
    } else if (r < 200){
      int h = r - 196;
      for (int c = 0; c < 64; ++c){
        float wsum = 0.f;
        for (int t = 0; t < 49; ++t) wsum += pos_w[(c & 15) * 49 + t];
        wrow[c] = (_Float16)(((c >> 4) == h) ? stats[c] * wsum : 0.f);
      }
      for (int k = 0; k < 16; ++k){
        float wsum = 0.f;
        for (int t = 0; t < 49; ++t) wsum += pos_w[k * 49 + t];
        bias += stats[64 + h * 16 + k] * wsum;
      }
    } else if (r < 208){
      for (int c = 0; c < 64; ++c) wrow[c] = (_Float16)0.f;
    } else {
      int hv = r - 208, h = hv >> 6, vv = hv & 63;
      // row position (vhi,kg,r2) holds v_actual = kg*16 + vhi*4 + r2
      int v = (((vv >> 2) & 3) << 4) | (((vv >> 4) & 3) << 2) | (vv & 3);
      for (int c = 0; c < 64; ++c)
        wrow[c] = (_Float16)(((c >> 4) == h) ? stats[c] * lcp[(size_t)(b * 16 + (c & 15)) * 64 + v] : 0.f);
      for (int k = 0; k < 16; ++k) bias += stats[64 + h * 16 + k] * lcp[(size_t)(b * 16 + k) * 64 + v];
    }
    Bbig[b * M2_ + r] = bias;
  }
}

// ---------------- K6: fused S-GEMM + y_c-GEMM + banded conv ----------
// 16x4 pixel tile, 4 waves (wave = pixel row). Coalesced f16 loads,
// XOR-swizzled vn LDS, [pix][tap*4+h] s LDS. Single out write.
__global__ __launch_bounds__(256, 3) void k_fused(
                        const _Float16* __restrict__ q16,
                        const _Float16* __restrict__ v16,
                        const float* __restrict__ stats,
                        const _Float16* __restrict__ Wbig,
                        const float* __restrict__ Bbig,
                        float* __restrict__ out){
  __shared__ _Float16 vn_s[220 * 64];      // 28160 B, XOR-swizzled (16B gran)
  __shared__ _Float16 s_s[4][16][204];     // 26112 B, [wave][pix][tap*4+h]

  const int b  = blockIdx.z;
  const int x0 = blockIdx.x * 16;
  const int y0 = blockIdx.y * 4;
  const int tid = threadIdx.x;
  const int lane = tid & 63, wid = tid >> 6;
  const int cl = lane & 15, kg = lane >> 4;
  const size_t bN = (size_t)b * N_;

  // ---- vn halo staging: 220 pos x 64 v, coalesced 16B loads ----
  for (int idx = tid; idx < 1760; idx += 256){
    int pos = idx >> 3, c8 = (idx & 7) << 3;
    int yy = pos / 22, xx = pos - yy * 22;
    int gy = y0 + yy - 3, gx = x0 + xx - 3;
    f16x8 val;
    #pragma unroll
    for (int j = 0; j < 8; ++j) val[j] = (_Float16)0.f;
    if ((unsigned)gy < 64u && (unsigned)gx < 64u)
      val = *reinterpret_cast<const f16x8*>(v16 + ((bN + gy * 64 + gx) << 6) + c8);
    int e = (pos << 6) + c8;
    *reinterpret_cast<f16x8*>(&vn_s[e ^ ((pos & 7) << 3)]) = val;
  }

  // ---- MFMA phase: 29 row-tiles for this wave's 16 pixels ----
  const int pix0 = (y0 + wid) * 64 + x0;
  const _Float16* qp = q16 + ((bN + pix0 + cl) << 6);
  f16x8 bfrag0 = *reinterpret_cast<const f16x8*>(qp + kg * 8);
  f16x8 bfrag1 = *reinterpret_cast<const f16x8*>(qp + 32 + kg * 8);
  const _Float16* Wb = Wbig + ((size_t)b * M2_ << 6);
  const float* Bb = Bbig + b * M2_;

  f32x4 acc[29];
  #pragma unroll
  for (int m = 0; m < 29; ++m){ acc[m][0]=0.f; acc[m][1]=0.f; acc[m][2]=0.f; acc[m][3]=0.f; }

  #pragma unroll
  for (int m = 0; m < 29; ++m){
    f16x8 a0 = *reinterpret_cast<const f16x8*>(Wb + ((m * 16 + cl) << 6) + kg * 8);
    f16x8 a1 = *reinterpret_cast<const f16x8*>(Wb + ((m * 16 + cl) << 6) + 32 + kg * 8);
    acc[m] = __builtin_amdgcn_mfma_f32_16x16x32_f16(a0, bfrag0, acc[m], 0, 0, 0);
    acc[m] = __builtin_amdgcn_mfma_f32_16x16x32_f16(a1, bfrag1, acc[m], 0, 0, 0);
  }

  // ---- S rows (+bias) -> per-wave LDS, layout [pix][tap*4+h] ----
  #pragma unroll
  for (int m = 0; m < 13; ++m){
    #pragma unroll
    for (int r = 0; r < 4; ++r){
      const int row = m * 16 + kg * 4 + r;
      if (row < 200){
        const int pos = (row < SROWS_) ? ((row % 49) * 4 + row / 49) : row;
        s_s[wid][cl][pos] = (_Float16)(acc[m][r] + Bb[row]);
      }
    }
  }
  __syncthreads();

  // ---- band phase: 49 taps, thread owns pixel cl x v in [kg*16, kg*16+16) ----
  f16x2 accB[4][8];
  #pragma unroll
  for (int h = 0; h < 4; ++h)
    #pragma unroll
    for (int j = 0; j < 8; ++j){ accB[h][j][0] = (_Float16)0.f; accB[h][j][1] = (_Float16)0.f; }

  const _Float16* srow = &s_s[wid][cl][0];
  #pragma unroll
  for (int dy = 0; dy < 7; ++dy){
    #pragma unroll
    for (int dx = 0; dx < 7; ++dx){
      const int tap = dy * 7 + dx;
      const int pos = (wid + dy) * 22 + (cl + dx);
      f16x4 s4 = *reinterpret_cast<const f16x4*>(srow + tap * 4);
      const int esw = ((pos << 6) + (kg << 4)) ^ ((pos & 7) << 3);
      f16x8 va = *reinterpret_cast<const f16x8*>(&vn_s[esw]);
      f16x8 vb = *reinterpret_cast<const f16x8*>(&vn_s[esw ^ 8]);
      #pragma unroll
      for (int h = 0; h < 4; ++h){
        f16x2 sh; sh[0] = s4[h]; sh[1] = s4[h];
        f16x2 p0 = __builtin_shufflevector(va, va, 0, 1);
        f16x2 p1 = __builtin_shufflevector(va, va, 2, 3);
        f16x2 p2 = __builtin_shufflevector(va, va, 4, 5);
        f16x2 p3 = __builtin_shufflevector(va, va, 6, 7);
        f16x2 p4 = __builtin_shufflevector(vb, vb, 0, 1);
        f16x2 p5 = __builtin_shufflevector(vb, vb, 2, 3);
        f16x2 p6 = __builtin_shufflevector(vb, vb, 4, 5);
        f16x2 p7 = __builtin_shufflevector(vb, vb, 6, 7);
        accB[h][0] = sh * p0 + accB[h][0];
        accB[h][1] = sh * p1 + accB[h][1];
        accB[h][2] = sh * p2 + accB[h][2];
        accB[h][3] = sh * p3 + accB[h][3];
        accB[h][4] = sh * p4 + accB[h][4];
        accB[h][5] = sh * p5 + accB[h][5];
        accB[h][6] = sh * p6 + accB[h][6];
        accB[h][7] = sh * p7 + accB[h][7];
      }
    }
  }

  // ---- merge y_c (MFMA acc, permuted rows) + a_v*band + c_v*ssum ----
  float* ob = out + ((size_t)b * 256) * N_ + pix0 + cl;
  #pragma unroll
  for (int h = 0; h < 4; ++h){
    const float ssum_h = (float)s_s[wid][cl][196 + h];
    #pragma unroll
    for (int vhi = 0; vhi < 4; ++vhi){
      const int m = 13 + h * 4 + vhi;
      f32x4 av = *reinterpret_cast<const f32x4*>(stats + 128 + kg * 16 + vhi * 4);
      f32x4 cv = *reinterpret_cast<const f32x4*>(stats + 192 + kg * 16 + vhi * 4);
      #pragma unroll
      for (int r = 0; r < 4; ++r){
        const int j = vhi * 4 + r;                  // v offset within kg chunk
        const int ch = h * 64 + kg * 16 + j;        // actual output channel
        const float band = (float)accB[h][j >> 1][j & 1];
        ob[(size_t)ch * N_] = acc[m][r] + Bb[208 + h * 64 + vhi * 16 + kg * 4 + r]
                              + av[r] * band + cv[r] * ssum_h;
      }
    }
  }
}

extern "C" void kernel_launch(void* const* d_in, const int* in_sizes, int n_in,
                              void* d_out, int out_size, void* d_ws, size_t ws_size,
                              hipStream_t stream){
  (void)in_sizes; (void)n_in; (void)out_size; (void)ws_size;
  const float* x  = (const float*)d_in[0];
  const float* Wq = (const float*)d_in[1];
  const float* Wk = (const float*)d_in[2];
  const float* Wv = (const float*)d_in[3];
  const float* gq = (const float*)d_in[4];
  const float* bq = (const float*)d_in[5];
  const float* gv = (const float*)d_in[6];
  const float* bv = (const float*)d_in[7];
  const float* pw = (const float*)d_in[8];
  const float* pb = (const float*)d_in[9];
  float* out = (float*)d_out;

  char* ws = (char*)d_ws;
  _Float16* Wcat = (_Float16*)ws;                               // 73,728 B
  float*    P    = (float*)(ws + 131072);                       // 37,748,736 B
  size_t off = 131072 + (size_t)M_ * NT_ * 4;
  _Float16* q16  = (_Float16*)(ws + off);  off += (size_t)NT_ * 64 * 2;       // 8,388,608
  _Float16* v16  = (_Float16*)(ws + off);  off += (size_t)NT_ * 64 * 2;       // 8,388,608
  _Float16* Wbig = (_Float16*)(ws + off);  off += (size_t)B_ * M2_ * 64 * 2;  // 950,272
  float*    Bbig = (float*)(ws + off);     off += (size_t)B_ * M2_ * 4;       // 29,696
  float*    stats   = (float*)(ws + off);  off += 256 * 4;
  float*    kstat   = (float*)(ws + off);  off += 512 * 4;
  float*    lcp     = (float*)(ws + off);  off += 256 * 64 * 4;
  float*    lc_part = (float*)(ws + off);  off += 1024 * 64 * 4;
  float*    bnpart  = (float*)(ws + off);  off += 1024 * 2 * 4;

  k_pack_w   <<<144, 256, 0, stream>>>(Wq, Wk, Wv, Wcat);
  k_proj     <<<1024, 256, 0, stream>>>(x, Wcat, P, q16, v16);
  k_bn1      <<<1024, 256, 0, stream>>>(P, bnpart);
  k_bn2      <<<1, 128, 0, stream>>>(bnpart, gq, bq, gv, bv, stats);
  k_softstats<<<256, 256, 0, stream>>>(P, kstat);
  k_lam1     <<<1024, 256, 0, stream>>>(P, kstat, lc_part);
  k_lam2     <<<1, 256, 0, stream>>>(lc_part, stats, pb, lcp);
  k_makeW    <<<16, 256, 0, stream>>>(stats, lcp, pw, Wbig, Bbig);
  dim3 g6(4, 16, 16);
  k_fused    <<<g6, 256, 0, stream>>>(q16, v16, stats, Wbig, Bbig, out);
}

// Round 5
// 180.438 us; speedup vs baseline: 1.6934x; 1.0907x over previous
//
#include <hip/hip_runtime.h>

// LambdaLayer2D: B=16, C=256, H=W=64, K=16, HEADS=4, U=1, V=64, R=7
#define B_ 16
#define C_ 256
#define N_ 4096            // H*W
#define NT_ 65536          // B*N
#define M2_ 464            // fused rows: 196 s + 4 ssum + 8 pad + 256 y_c
#define SROWS_ 196

typedef _Float16 f16x8 __attribute__((ext_vector_type(8)));
typedef _Float16 f16x4 __attribute__((ext_vector_type(4)));
typedef _Float16 f16x2 __attribute__((ext_vector_type(2)));
typedef float    f32x4 __attribute__((ext_vector_type(4)));

__device__ __forceinline__ float waveSum(float v){
  #pragma unroll
  for (int off = 32; off > 0; off >>= 1) v += __shfl_xor(v, off, 64);
  return v;
}
__device__ __forceinline__ float waveMax(float v){
  #pragma unroll
  for (int off = 32; off > 0; off >>= 1) v = fmaxf(v, __shfl_xor(v, off, 64));
  return v;
}

// ---------------- K0: pack Wq|Wk|Wv -> fp16 [144][256] ----------------
__global__ void k_pack_w(const float* __restrict__ Wq, const float* __restrict__ Wk,
                         const float* __restrict__ Wv, _Float16* __restrict__ Wcat){
  int idx = blockIdx.x * 256 + threadIdx.x;   // 144*256 = 36864
  int row = idx >> 8, col = idx & 255;
  float v;
  if (row < 64)      v = Wq[row * 256 + col];
  else if (row < 80) v = Wk[(row - 64) * 256 + col];
  else               v = Wv[(row - 80) * 256 + col];
  Wcat[idx] = (_Float16)v;
}

// ---------------- K1: projection GEMM + BN partials -------------------
// Emits: kP[16][NT] f32 (k rows), q16/v16 pixel-major f16, and per-block
// BN partial sums (sum, sumsq) for the 128 BN'd channels.
__global__ __launch_bounds__(256) void k_proj(const float* __restrict__ x,
                                              const _Float16* __restrict__ Wcat,
                                              float* __restrict__ kP,
                                              _Float16* __restrict__ q16,
                                              _Float16* __restrict__ v16,
                                              float* __restrict__ bnpart){
  __shared__ float bsumW[4][128];
  __shared__ float bssqW[4][128];

  const int lane = threadIdx.x & 63;
  const int wid  = threadIdx.x >> 6;
  const int tile = blockIdx.x * 4 + wid;   // 0..4095
  const int j0 = tile << 4;
  const int b  = j0 >> 12;
  const int n0 = j0 & 4095;
  const int cl = lane & 15;
  const int kg = lane >> 4;

  f32x4 acc[9];
  #pragma unroll
  for (int m = 0; m < 9; ++m){ acc[m][0]=0.f; acc[m][1]=0.f; acc[m][2]=0.f; acc[m][3]=0.f; }

  const float* xb = x + (size_t)b * C_ * N_ + n0 + cl;
  #pragma unroll
  for (int kk = 0; kk < 8; ++kk){
    const int kb = kk * 32 + kg * 8;
    f16x8 bfrag;
    #pragma unroll
    for (int jj = 0; jj < 8; ++jj) bfrag[jj] = (_Float16)xb[(size_t)(kb + jj) * N_];
    #pragma unroll
    for (int m = 0; m < 9; ++m){
      f16x8 afrag = *reinterpret_cast<const f16x8*>(Wcat + ((m * 16 + cl) << 8) + kb);
      acc[m] = __builtin_amdgcn_mfma_f32_16x16x32_f16(afrag, bfrag, acc[m], 0, 0, 0);
    }
  }

  // k rows (Wcat rows 64..79) -> kP f32
  #pragma unroll
  for (int r = 0; r < 4; ++r)
    kP[(size_t)(kg * 4 + r) * NT_ + j0 + cl] = acc[4][r];

  // pixel-major f16 q/v
  const size_t prow = ((size_t)(j0 + cl)) << 6;
  #pragma unroll
  for (int m = 0; m < 4; ++m){
    f16x4 h4;
    #pragma unroll
    for (int r = 0; r < 4; ++r) h4[r] = (_Float16)acc[m][r];
    *reinterpret_cast<f16x4*>(q16 + prow + m * 16 + kg * 4) = h4;
  }
  #pragma unroll
  for (int m = 5; m < 9; ++m){
    f16x4 h4;
    #pragma unroll
    for (int r = 0; r < 4; ++r) h4[r] = (_Float16)acc[m][r];
    *reinterpret_cast<f16x4*>(v16 + prow + (m - 5) * 16 + kg * 4) = h4;
  }

  // BN partials: reduce each row over this wave's 16 pixels (shfl within
  // the 16-lane cl group), deposit per-wave, combine, write per-block.
  #pragma unroll
  for (int m = 0; m < 9; ++m){
    if (m == 4) continue;
    #pragma unroll
    for (int r = 0; r < 4; ++r){
      float sv = acc[m][r];
      float sq = sv * sv;
      #pragma unroll
      for (int off = 1; off < 16; off <<= 1){
        sv += __shfl_xor(sv, off, 64);
        sq += __shfl_xor(sq, off, 64);
      }
      if (cl == 0){
        int idx = ((m < 4) ? m * 16 : (m - 5) * 16 + 64) + kg * 4 + r;
        bsumW[wid][idx] = sv;
        bssqW[wid][idx] = sq;
      }
    }
  }
  __syncthreads();
  if (threadIdx.x < 128){
    int i = threadIdx.x;
    float s  = bsumW[0][i] + bsumW[1][i] + bsumW[2][i] + bsumW[3][i];
    float sq = bssqW[0][i] + bssqW[1][i] + bssqW[2][i] + bssqW[3][i];
    bnpart[(size_t)i * 1024 + blockIdx.x]         = s;
    bnpart[(size_t)(i + 128) * 1024 + blockIdx.x] = sq;
  }
}

// ---------------- K2: finalize BN -> folded affine --------------------
// stats layout: [0:64) aq, [64:128) cq, [128:192) av, [192:256) cv
__global__ void k_bn2(const float* __restrict__ bnpart,
                      const float* __restrict__ gq, const float* __restrict__ bq,
                      const float* __restrict__ gv, const float* __restrict__ bv,
                      float* __restrict__ stats){
  const int ch = blockIdx.x;       // 0..127
  const int t = threadIdx.x;
  float s = 0.f, ss = 0.f;
  #pragma unroll
  for (int k = 0; k < 4; ++k){
    int bk = t + k * 256;
    s  += bnpart[(size_t)ch * 1024 + bk];
    ss += bnpart[(size_t)(ch + 128) * 1024 + bk];
  }
  __shared__ float r0[4], r1[4];
  const int lane = t & 63, wid = t >> 6;
  s = waveSum(s); ss = waveSum(ss);
  if (lane == 0){ r0[wid] = s; r1[wid] = ss; }
  __syncthreads();
  if (t == 0){
    s  = r0[0] + r0[1] + r0[2] + r0[3];
    ss = r1[0] + r1[1] + r1[2] + r1[3];
    float mean = s * (1.f / NT_);
    float var  = ss * (1.f / NT_) - mean * mean;   // biased
    float rs = rsqrtf(var + 1e-5f);
    if (ch < 64){
      float a = rs * gq[ch];
      stats[ch] = a; stats[64 + ch] = bq[ch] - mean * a;
    } else {
      int v = ch - 64;
      float a = rs * gv[v];
      stats[128 + v] = a; stats[192 + v] = bv[v] - mean * a;
    }
  }
}

// ---------------- K3: softmax row stats (max, 1/sumexp) --------------
__global__ void k_softstats(const float* __restrict__ kP, float* __restrict__ kstat){
  const int bid = blockIdx.x;                   // b*16 + kc
  const int b = bid >> 4, kc = bid & 15;
  const float* row = kP + (size_t)kc * NT_ + b * N_;
  const int lane = threadIdx.x & 63, wid = threadIdx.x >> 6;
  __shared__ float sm[4], sb[4];
  float m = -1e30f;
  for (int i = threadIdx.x; i < N_; i += 256) m = fmaxf(m, row[i]);
  m = waveMax(m);
  if (lane == 0) sm[wid] = m;
  __syncthreads();
  float mg = fmaxf(fmaxf(sm[0], sm[1]), fmaxf(sm[2], sm[3]));
  float s = 0.f;
  for (int i = threadIdx.x; i < N_; i += 256) s += __expf(row[i] - mg);
  s = waveSum(s);
  if (lane == 0) sb[wid] = s;
  __syncthreads();
  if (threadIdx.x == 0){
    kstat[bid] = mg;
    kstat[256 + bid] = 1.f / (sb[0] + sb[1] + sb[2] + sb[3]);
  }
}

// ---------------- K4: lambda_c partials: all 16 kc x 64 v per slice ---
// Block = (b, slice of 256 px). Thread (kc, vg) accumulates 4 v values.
// sk staged in LDS per 64-px chunk; v read from pixel-major v16.
__global__ __launch_bounds__(256) void k_lam1(const float* __restrict__ kP,
                          const _Float16* __restrict__ v16,
                          const float* __restrict__ kstat,
                          float* __restrict__ lc_part){
  const int blk = blockIdx.x;                 // b*16 + sl
  const int b = blk >> 4, sl = blk & 15;
  const int tid = threadIdx.x;
  const int kc = tid >> 4;                    // 0..15
  const int vg = tid & 15;                    // v-group of 4
  __shared__ float skb[16][64];

  const float km = kstat[b * 16 + kc];
  const float ki = kstat[256 + b * 16 + kc];
  const float* kpt = kP + (size_t)kc * NT_ + b * N_ + sl * 256;
  const _Float16* vbase = v16 + (((size_t)(b * N_ + sl * 256)) << 6);

  float S0 = 0.f, S1 = 0.f, S2 = 0.f, S3 = 0.f;
  for (int ch = 0; ch < 4; ++ch){
    // stage sk for this 64-px chunk (thread covers its kc, px vg*4..+3)
    float4 kv = *reinterpret_cast<const float4*>(kpt + ch * 64 + vg * 4);
    skb[kc][vg * 4 + 0] = __expf(kv.x - km) * ki;
    skb[kc][vg * 4 + 1] = __expf(kv.y - km) * ki;
    skb[kc][vg * 4 + 2] = __expf(kv.z - km) * ki;
    skb[kc][vg * 4 + 3] = __expf(kv.w - km) * ki;
    __syncthreads();
    #pragma unroll 8
    for (int j = 0; j < 64; ++j){
      f16x4 v4 = *reinterpret_cast<const f16x4*>(vbase + (((size_t)(ch * 64 + j)) << 6) + vg * 4);
      float sk = skb[kc][j];
      S0 += sk * (float)v4[0];
      S1 += sk * (float)v4[1];
      S2 += sk * (float)v4[2];
      S3 += sk * (float)v4[3];
    }
    __syncthreads();
  }
  float4 w; w.x = S0; w.y = S1; w.z = S2; w.w = S3;
  *reinterpret_cast<float4*>(lc_part + (size_t)blk * 1024 + kc * 64 + vg * 4) = w;
}

// ---------------- K5: build per-batch big weight [464][64] -----------
// (lambda_c finalize folded in via LDS). rows 0..195: s rows (h,tap);
// 196..199: ssum rows (h); 200..207: zero; 208..463: y_c rows (h, perm v)
__global__ void k_makeW(const float* __restrict__ stats, const float* __restrict__ lc_part,
                        const float* __restrict__ pos_w, const float* __restrict__ pos_b,
                        _Float16* __restrict__ Wbig, float* __restrict__ Bbig){
  const int b = blockIdx.x;
  __shared__ float lcq[16][64];
  for (int o = threadIdx.x; o < 1024; o += 256){
    int kc = o >> 6, v = o & 63;
    float s = 0.f;
    #pragma unroll
    for (int sl = 0; sl < 16; ++sl) s += lc_part[(size_t)(b * 16 + sl) * 1024 + o];
    lcq[kc][v] = stats[128 + v] * s + stats[192 + v] + pos_b[kc];
  }
  __syncthreads();

  for (int r = threadIdx.x; r < M2_; r += 256){
    float bias = 0.f;
    _Float16* wrow = Wbig + ((size_t)(b * M2_ + r) << 6);
    if (r < SROWS_){
      int h = r / 49, tap = r % 49;
      for (int c = 0; c < 64; ++c)
        wrow[c] = (_Float16)(((c >> 4) == h) ? stats[c] * pos_w[(c & 15) * 49 + tap] : 0.f);
      for (int k = 0; k < 16; ++k) bias += stats[64 + h * 16 + k] * pos_w[k * 49 + tap];
    } else if (r < 200){
      int h = r - 196;
      for (int c = 0; c < 64; ++c){
        float wsum = 0.f;
        for (int t = 0; t < 49; ++t) wsum += pos_w[(c & 15) * 49 + t];
        wrow[c] = (_Float16)(((c >> 4) == h) ? stats[c] * wsum : 0.f);
      }
      for (int k = 0; k < 16; ++k){
        float wsum = 0.f;
        for (int t = 0; t < 49; ++t) wsum += pos_w[k * 49 + t];
        bias += stats[64 + h * 16 + k] * wsum;
      }
    } else if (r < 208){
      for (int c = 0; c < 64; ++c) wrow[c] = (_Float16)0.f;
    } else {
      int hv = r - 208, h = hv >> 6, vv = hv & 63;
      // row position (vhi,kg,r2) holds v_actual = kg*16 + vhi*4 + r2
      int v = (((vv >> 2) & 3) << 4) | (((vv >> 4) & 3) << 2) | (vv & 3);
      for (int c = 0; c < 64; ++c)
        wrow[c] = (_Float16)(((c >> 4) == h) ? stats[c] * lcq[c & 15][v] : 0.f);
      for (int k = 0; k < 16; ++k) bias += stats[64 + h * 16 + k] * lcq[k][v];
    }
    Bbig[b * M2_ + r] = bias;
  }
}

// ---------------- K6: fused S-GEMM + y_c-GEMM + banded conv ----------
// 8x8 pixel tile, 4 waves (wave = 8x2 pixel strip). LDS 50,688 B ->
// 3 blocks/CU. XOR-swizzled vn LDS, [pix][tap*4+h] s LDS, single write.
__global__ __launch_bounds__(256, 3) void k_fused(
                        const _Float16* __restrict__ q16,
                        const _Float16* __restrict__ v16,
                        const float* __restrict__ stats,
                        const _Float16* __restrict__ Wbig,
                        const float* __restrict__ Bbig,
                        float* __restrict__ out){
  __shared__ _Float16 vn_s[196 * 64];      // 25088 B, XOR-swizzled (16B gran)
  __shared__ _Float16 s_s[4][16][200];     // 25600 B, [wave][pix][tap*4+h]

  const int b  = blockIdx.z;
  const int x0 = blockIdx.x * 8;
  const int y0 = blockIdx.y * 8;
  const int tid = threadIdx.x;
  const int lane = tid & 63, wid = tid >> 6;
  const int cl = lane & 15, kg = lane >> 4;
  const size_t bN = (size_t)b * N_;

  // ---- vn halo staging: 196 pos x 64 v, coalesced 16B loads ----
  for (int idx = tid; idx < 1568; idx += 256){
    int pos = idx >> 3, c8 = (idx & 7) << 3;
    int yy = pos / 14, xx = pos - yy * 14;
    int gy = y0 + yy - 3, gx = x0 + xx - 3;
    f16x8 val;
    #pragma unroll
    for (int j = 0; j < 8; ++j) val[j] = (_Float16)0.f;
    if ((unsigned)gy < 64u && (unsigned)gx < 64u)
      val = *reinterpret_cast<const f16x8*>(v16 + ((bN + gy * 64 + gx) << 6) + c8);
    int e = (pos << 6) + c8;
    *reinterpret_cast<f16x8*>(&vn_s[e ^ ((pos & 7) << 3)]) = val;
  }

  // ---- MFMA phase: 29 row-tiles for this wave's 16 pixels ----
  const int py = (wid << 1) | (cl >> 3);
  const int px = cl & 7;
  const int pix = (y0 + py) * 64 + x0 + px;
  const _Float16* qp = q16 + ((bN + pix) << 6);
  f16x8 bfrag0 = *reinterpret_cast<const f16x8*>(qp + kg * 8);
  f16x8 bfrag1 = *reinterpret_cast<const f16x8*>(qp + 32 + kg * 8);
  const _Float16* Wb = Wbig + ((size_t)b * M2_ << 6);
  const float* Bb = Bbig + b * M2_;

  f32x4 acc[29];
  #pragma unroll
  for (int m = 0; m < 29; ++m){ acc[m][0]=0.f; acc[m][1]=0.f; acc[m][2]=0.f; acc[m][3]=0.f; }

  #pragma unroll
  for (int m = 0; m < 29; ++m){
    f16x8 a0 = *reinterpret_cast<const f16x8*>(Wb + ((m * 16 + cl) << 6) + kg * 8);
    f16x8 a1 = *reinterpret_cast<const f16x8*>(Wb + ((m * 16 + cl) << 6) + 32 + kg * 8);
    acc[m] = __builtin_amdgcn_mfma_f32_16x16x32_f16(a0, bfrag0, acc[m], 0, 0, 0);
    acc[m] = __builtin_amdgcn_mfma_f32_16x16x32_f16(a1, bfrag1, acc[m], 0, 0, 0);
  }

  // ---- S rows (+bias) -> per-wave LDS, layout [pix][tap*4+h] ----
  #pragma unroll
  for (int m = 0; m < 13; ++m){
    #pragma unroll
    for (int r = 0; r < 4; ++r){
      const int row = m * 16 + kg * 4 + r;
      if (row < 200){
        const int pos = (row < SROWS_) ? ((row % 49) * 4 + row / 49) : row;
        s_s[wid][cl][pos] = (_Float16)(acc[m][r] + Bb[row]);
      }
    }
  }
  __syncthreads();

  // ---- band phase: 49 taps, thread owns pixel cl x v in [kg*16,+16) ----
  f16x2 accB[4][8];
  #pragma unroll
  for (int h = 0; h < 4; ++h)
    #pragma unroll
    for (int j = 0; j < 8; ++j){ accB[h][j][0] = (_Float16)0.f; accB[h][j][1] = (_Float16)0.f; }

  const _Float16* srow = &s_s[wid][cl][0];
  #pragma unroll
  for (int dy = 0; dy < 7; ++dy){
    #pragma unroll
    for (int dx = 0; dx < 7; ++dx){
      const int tap = dy * 7 + dx;
      const int pos = (py + dy) * 14 + (px + dx);
      f16x4 s4 = *reinterpret_cast<const f16x4*>(srow + tap * 4);
      const int esw = ((pos << 6) + (kg << 4)) ^ ((pos & 7) << 3);
      f16x8 va = *reinterpret_cast<const f16x8*>(&vn_s[esw]);
      f16x8 vb = *reinterpret_cast<const f16x8*>(&vn_s[esw ^ 8]);
      #pragma unroll
      for (int h = 0; h < 4; ++h){
        f16x2 sh; sh[0] = s4[h]; sh[1] = s4[h];
        f16x2 p0 = __builtin_shufflevector(va, va, 0, 1);
        f16x2 p1 = __builtin_shufflevector(va, va, 2, 3);
        f16x2 p2 = __builtin_shufflevector(va, va, 4, 5);
        f16x2 p3 = __builtin_shufflevector(va, va, 6, 7);
        f16x2 p4 = __builtin_shufflevector(vb, vb, 0, 1);
        f16x2 p5 = __builtin_shufflevector(vb, vb, 2, 3);
        f16x2 p6 = __builtin_shufflevector(vb, vb, 4, 5);
        f16x2 p7 = __builtin_shufflevector(vb, vb, 6, 7);
        accB[h][0] = sh * p0 + accB[h][0];
        accB[h][1] = sh * p1 + accB[h][1];
        accB[h][2] = sh * p2 + accB[h][2];
        accB[h][3] = sh * p3 + accB[h][3];
        accB[h][4] = sh * p4 + accB[h][4];
        accB[h][5] = sh * p5 + accB[h][5];
        accB[h][6] = sh * p6 + accB[h][6];
        accB[h][7] = sh * p7 + accB[h][7];
      }
    }
  }

  // ---- merge y_c (MFMA acc, permuted rows) + a_v*band + c_v*ssum ----
  float* ob = out + ((size_t)b * 256) * N_ + pix;
  #pragma unroll
  for (int h = 0; h < 4; ++h){
    const float ssum_h = (float)s_s[wid][cl][196 + h];
    #pragma unroll
    for (int vhi = 0; vhi < 4; ++vhi){
      const int m = 13 + h * 4 + vhi;
      f32x4 av = *reinterpret_cast<const f32x4*>(stats + 128 + kg * 16 + vhi * 4);
      f32x4 cv = *reinterpret_cast<const f32x4*>(stats + 192 + kg * 16 + vhi * 4);
      #pragma unroll
      for (int r = 0; r < 4; ++r){
        const int j = vhi * 4 + r;                  // v offset within kg chunk
        const int ch = h * 64 + kg * 16 + j;        // actual output channel
        const float band = (float)accB[h][j >> 1][j & 1];
        ob[(size_t)ch * N_] = acc[m][r] + Bb[208 + h * 64 + vhi * 16 + kg * 4 + r]
                              + av[r] * band + cv[r] * ssum_h;
      }
    }
  }
}

extern "C" void kernel_launch(void* const* d_in, const int* in_sizes, int n_in,
                              void* d_out, int out_size, void* d_ws, size_t ws_size,
                              hipStream_t stream){
  (void)in_sizes; (void)n_in; (void)out_size; (void)ws_size;
  const float* x  = (const float*)d_in[0];
  const float* Wq = (const float*)d_in[1];
  const float* Wk = (const float*)d_in[2];
  const float* Wv = (const float*)d_in[3];
  const float* gq = (const float*)d_in[4];
  const float* bq = (const float*)d_in[5];
  const float* gv = (const float*)d_in[6];
  const float* bv = (const float*)d_in[7];
  const float* pw = (const float*)d_in[8];
  const float* pb = (const float*)d_in[9];
  float* out = (float*)d_out;

  char* ws = (char*)d_ws;
  size_t off = 0;
  _Float16* Wcat = (_Float16*)(ws + off);  off += 131072;                     // 73,728 used
  float*    kP   = (float*)(ws + off);     off += (size_t)16 * NT_ * 4;       // 4,194,304
  _Float16* q16  = (_Float16*)(ws + off);  off += (size_t)NT_ * 64 * 2;       // 8,388,608
  _Float16* v16  = (_Float16*)(ws + off);  off += (size_t)NT_ * 64 * 2;       // 8,388,608
  _Float16* Wbig = (_Float16*)(ws + off);  off += (size_t)B_ * M2_ * 64 * 2;  // 950,272
  float*    Bbig = (float*)(ws + off);     off += (size_t)B_ * M2_ * 4 + 2048;// 29,696
  float*    stats   = (float*)(ws + off);  off += 1024;
  float*    kstat   = (float*)(ws + off);  off += 2048;
  float*    lc_part = (float*)(ws + off);  off += (size_t)256 * 1024 * 4;     // 1,048,576
  float*    bnpart  = (float*)(ws + off);  off += (size_t)256 * 1024 * 4;     // 1,048,576

  k_pack_w   <<<144, 256, 0, stream>>>(Wq, Wk, Wv, Wcat);
  k_proj     <<<1024, 256, 0, stream>>>(x, Wcat, kP, q16, v16, bnpart);
  k_bn2      <<<128, 256, 0, stream>>>(bnpart, gq, bq, gv, bv, stats);
  k_softstats<<<256, 256, 0, stream>>>(kP, kstat);
  k_lam1     <<<256, 256, 0, stream>>>(kP, v16, kstat, lc_part);
  k_makeW    <<<16, 256, 0, stream>>>(stats, lc_part, pw, pb, Wbig, Bbig);
  dim3 g6(8, 8, 16);
  k_fused    <<<g6, 256, 0, stream>>>(q16, v16, stats, Wbig, Bbig, out);
}

// Round 6
// 171.132 us; speedup vs baseline: 1.7855x; 1.0544x over previous
//
#include <hip/hip_runtime.h>

// LambdaLayer2D: B=16, C=256, H=W=64, K=16, HEADS=4, U=1, V=64, R=7
#define B_ 16
#define C_ 256
#define N_ 4096            // H*W
#define NT_ 65536          // B*N
#define M2_ 464            // fused rows: 196 s + 4 ssum + 8 pad + 256 y_c
#define SROWS_ 196

typedef _Float16 f16x8 __attribute__((ext_vector_type(8)));
typedef _Float16 f16x4 __attribute__((ext_vector_type(4)));
typedef _Float16 f16x2 __attribute__((ext_vector_type(2)));
typedef float    f32x4 __attribute__((ext_vector_type(4)));

__device__ __forceinline__ float waveSum(float v){
  #pragma unroll
  for (int off = 32; off > 0; off >>= 1) v += __shfl_xor(v, off, 64);
  return v;
}

// ---------------- K0: pack Wq|Wk|Wv -> fp16 [144][256] ----------------
__global__ void k_pack_w(const float* __restrict__ Wq, const float* __restrict__ Wk,
                         const float* __restrict__ Wv, _Float16* __restrict__ Wcat){
  int idx = blockIdx.x * 256 + threadIdx.x;   // 144*256 = 36864
  int row = idx >> 8, col = idx & 255;
  float v;
  if (row < 64)      v = Wq[row * 256 + col];
  else if (row < 80) v = Wk[(row - 64) * 256 + col];
  else               v = Wv[(row - 80) * 256 + col];
  Wcat[idx] = (_Float16)v;
}

// ---------------- K1: projection GEMM + BN partials + exp(k) ---------
// Emits: q16/v16 pixel-major f16, ek16[n][16] = exp(k) f16, per-block BN
// partial sums for the 128 BN'd channels, per-block sum-exp partials.
__global__ __launch_bounds__(256) void k_proj(const float* __restrict__ x,
                                              const _Float16* __restrict__ Wcat,
                                              _Float16* __restrict__ q16,
                                              _Float16* __restrict__ v16,
                                              _Float16* __restrict__ ek16,
                                              float* __restrict__ bnpart,
                                              float* __restrict__ kpart){
  __shared__ float bsumW[4][128];
  __shared__ float bssqW[4][128];
  __shared__ float ksumW[4][16];

  const int lane = threadIdx.x & 63;
  const int wid  = threadIdx.x >> 6;
  const int tile = blockIdx.x * 4 + wid;   // 0..4095
  const int j0 = tile << 4;
  const int b  = j0 >> 12;
  const int n0 = j0 & 4095;
  const int cl = lane & 15;
  const int kg = lane >> 4;

  f32x4 acc[9];
  #pragma unroll
  for (int m = 0; m < 9; ++m){ acc[m][0]=0.f; acc[m][1]=0.f; acc[m][2]=0.f; acc[m][3]=0.f; }

  const float* xb = x + (size_t)b * C_ * N_ + n0 + cl;
  #pragma unroll
  for (int kk = 0; kk < 8; ++kk){
    const int kb = kk * 32 + kg * 8;
    f16x8 bfrag;
    #pragma unroll
    for (int jj = 0; jj < 8; ++jj) bfrag[jj] = (_Float16)xb[(size_t)(kb + jj) * N_];
    #pragma unroll
    for (int m = 0; m < 9; ++m){
      f16x8 afrag = *reinterpret_cast<const f16x8*>(Wcat + ((m * 16 + cl) << 8) + kb);
      acc[m] = __builtin_amdgcn_mfma_f32_16x16x32_f16(afrag, bfrag, acc[m], 0, 0, 0);
    }
  }

  // exp(k) rows (Wcat rows 64..79): pixel-major f16 + wave partial sums
  {
    float eks[4];
    f16x4 h4;
    #pragma unroll
    for (int r = 0; r < 4; ++r){ eks[r] = __expf(acc[4][r]); h4[r] = (_Float16)eks[r]; }
    *reinterpret_cast<f16x4*>(ek16 + (((size_t)(j0 + cl)) << 4) + kg * 4) = h4;
    #pragma unroll
    for (int r = 0; r < 4; ++r){
      #pragma unroll
      for (int off = 1; off < 16; off <<= 1) eks[r] += __shfl_xor(eks[r], off, 64);
      if (cl == 0) ksumW[wid][kg * 4 + r] = eks[r];
    }
  }

  // pixel-major f16 q/v
  const size_t prow = ((size_t)(j0 + cl)) << 6;
  #pragma unroll
  for (int m = 0; m < 4; ++m){
    f16x4 h4;
    #pragma unroll
    for (int r = 0; r < 4; ++r) h4[r] = (_Float16)acc[m][r];
    *reinterpret_cast<f16x4*>(q16 + prow + m * 16 + kg * 4) = h4;
  }
  #pragma unroll
  for (int m = 5; m < 9; ++m){
    f16x4 h4;
    #pragma unroll
    for (int r = 0; r < 4; ++r) h4[r] = (_Float16)acc[m][r];
    *reinterpret_cast<f16x4*>(v16 + prow + (m - 5) * 16 + kg * 4) = h4;
  }

  // BN partials: reduce each row over this wave's 16 pixels
  #pragma unroll
  for (int m = 0; m < 9; ++m){
    if (m == 4) continue;
    #pragma unroll
    for (int r = 0; r < 4; ++r){
      float sv = acc[m][r];
      float sq = sv * sv;
      #pragma unroll
      for (int off = 1; off < 16; off <<= 1){
        sv += __shfl_xor(sv, off, 64);
        sq += __shfl_xor(sq, off, 64);
      }
      if (cl == 0){
        int idx = ((m < 4) ? m * 16 : (m - 5) * 16 + 64) + kg * 4 + r;
        bsumW[wid][idx] = sv;
        bssqW[wid][idx] = sq;
      }
    }
  }
  __syncthreads();
  if (threadIdx.x < 128){
    int i = threadIdx.x;
    float s  = bsumW[0][i] + bsumW[1][i] + bsumW[2][i] + bsumW[3][i];
    float sq = bssqW[0][i] + bssqW[1][i] + bssqW[2][i] + bssqW[3][i];
    bnpart[(size_t)i * 1024 + blockIdx.x]         = s;
    bnpart[(size_t)(i + 128) * 1024 + blockIdx.x] = sq;
  } else if (threadIdx.x < 144){
    int t = threadIdx.x - 128;    // kc 0..15
    float s = ksumW[0][t] + ksumW[1][t] + ksumW[2][t] + ksumW[3][t];
    kpart[(size_t)((blockIdx.x >> 6) * 16 + t) * 64 + (blockIdx.x & 63)] = s;
  }
}

// ---------------- K2: finalize BN affine + sum-exp --------------------
// blocks 0..127: BN channel; block 128: kstat[256] = 1/sumexp
// stats layout: [0:64) aq, [64:128) cq, [128:192) av, [192:256) cv
__global__ void k_bn2(const float* __restrict__ bnpart, const float* __restrict__ kpart,
                      const float* __restrict__ gq, const float* __restrict__ bq,
                      const float* __restrict__ gv, const float* __restrict__ bv,
                      float* __restrict__ stats, float* __restrict__ kstat){
  if (blockIdx.x == 128){
    int t = threadIdx.x;          // 0..255 = b*16+kc
    float s = 0.f;
    #pragma unroll
    for (int i = 0; i < 64; ++i) s += kpart[(size_t)t * 64 + i];
    kstat[t] = 1.f / s;
    return;
  }
  const int ch = blockIdx.x;       // 0..127
  const int t = threadIdx.x;
  float s = 0.f, ss = 0.f;
  #pragma unroll
  for (int k = 0; k < 4; ++k){
    int bk = t + k * 256;
    s  += bnpart[(size_t)ch * 1024 + bk];
    ss += bnpart[(size_t)(ch + 128) * 1024 + bk];
  }
  __shared__ float r0[4], r1[4];
  const int lane = t & 63, wid = t >> 6;
  s = waveSum(s); ss = waveSum(ss);
  if (lane == 0){ r0[wid] = s; r1[wid] = ss; }
  __syncthreads();
  if (t == 0){
    s  = r0[0] + r0[1] + r0[2] + r0[3];
    ss = r1[0] + r1[1] + r1[2] + r1[3];
    float mean = s * (1.f / NT_);
    float var  = ss * (1.f / NT_) - mean * mean;   // biased
    float rs = rsqrtf(var + 1e-5f);
    if (ch < 64){
      float a = rs * gq[ch];
      stats[ch] = a; stats[64 + ch] = bq[ch] - mean * a;
    } else {
      int v = ch - 64;
      float a = rs * gv[v];
      stats[128 + v] = a; stats[192 + v] = bv[v] - mean * a;
    }
  }
}

// ---------------- K3: lambda_c partials: all 16 kc x 64 v per slice ---
// Block = (b, slice of 256 px). Thread (kc, vg) accumulates 4 v values.
// sk (= exp(k)/sumexp) staged in LDS per 64-px chunk from f16 ek16.
__global__ __launch_bounds__(256) void k_lam1(const _Float16* __restrict__ ek16,
                          const _Float16* __restrict__ v16,
                          const float* __restrict__ kstat,
                          float* __restrict__ lc_part){
  const int blk = blockIdx.x;                 // b*16 + sl
  const int b = blk >> 4, sl = blk & 15;
  const int tid = threadIdx.x;
  const int kc = tid >> 4;                    // 0..15
  const int vg = tid & 15;                    // v-group of 4
  __shared__ float skb[16][65];
  __shared__ float kis[16];

  if (tid < 16) kis[tid] = kstat[b * 16 + tid];
  __syncthreads();

  const size_t base = (size_t)(b * N_ + sl * 256);
  const _Float16* vbase = v16 + (base << 6);

  float S0 = 0.f, S1 = 0.f, S2 = 0.f, S3 = 0.f;
  for (int ch = 0; ch < 4; ++ch){
    if (tid < 128){
      int px = tid >> 1, part = tid & 1;
      f16x8 e8 = *reinterpret_cast<const f16x8*>(ek16 + ((base + ch * 64 + px) << 4) + part * 8);
      #pragma unroll
      for (int j = 0; j < 8; ++j)
        skb[part * 8 + j][px] = (float)e8[j] * kis[part * 8 + j];
    }
    __syncthreads();
    #pragma unroll 8
    for (int j = 0; j < 64; ++j){
      f16x4 v4 = *reinterpret_cast<const f16x4*>(vbase + (((size_t)(ch * 64 + j)) << 6) + vg * 4);
      float sk = skb[kc][j];
      S0 += sk * (float)v4[0];
      S1 += sk * (float)v4[1];
      S2 += sk * (float)v4[2];
      S3 += sk * (float)v4[3];
    }
    __syncthreads();
  }
  float4 w; w.x = S0; w.y = S1; w.z = S2; w.w = S3;
  *reinterpret_cast<float4*>(lc_part + (size_t)blk * 1024 + kc * 64 + vg * 4) = w;
}

// ---------------- K4: build per-batch big weight [464][64] -----------
// rows 0..195: s rows (h,tap); 196..199: ssum rows (h); 200..207: zero;
// 208..463: y_c rows (h, permuted v). lambda_c finalize folded in.
__global__ void k_makeW(const float* __restrict__ stats, const float* __restrict__ lc_part,
                        const float* __restrict__ pos_w, const float* __restrict__ pos_b,
                        _Float16* __restrict__ Wbig, float* __restrict__ Bbig){
  const int b = blockIdx.x;
  __shared__ float lcq[16][64];
  for (int o = threadIdx.x; o < 1024; o += 256){
    int kc = o >> 6, v = o & 63;
    float s = 0.f;
    #pragma unroll
    for (int sl = 0; sl < 16; ++sl) s += lc_part[(size_t)(b * 16 + sl) * 1024 + o];
    lcq[kc][v] = stats[128 + v] * s + stats[192 + v] + pos_b[kc];
  }
  __syncthreads();

  for (int r = threadIdx.x; r < M2_; r += 256){
    float bias = 0.f;
    _Float16* wrow = Wbig + ((size_t)(b * M2_ + r) << 6);
    if (r < SROWS_){
      int h = r / 49, tap = r % 49;
      for (int c = 0; c < 64; ++c)
        wrow[c] = (_Float16)(((c >> 4) == h) ? stats[c] * pos_w[(c & 15) * 49 + tap] : 0.f);
      for (int k = 0; k < 16; ++k) bias += stats[64 + h * 16 + k] * pos_w[k * 49 + tap];
    } else if (r < 200){
      int h = r - 196;
      for (int c = 0; c < 64; ++c){
        float wsum = 0.f;
        for (int t = 0; t < 49; ++t) wsum += pos_w[(c & 15) * 49 + t];
        wrow[c] = (_Float16)(((c >> 4) == h) ? stats[c] * wsum : 0.f);
      }
      for (int k = 0; k < 16; ++k){
        float wsum = 0.f;
        for (int t = 0; t < 49; ++t) wsum += pos_w[k * 49 + t];
        bias += stats[64 + h * 16 + k] * wsum;
      }
    } else if (r < 208){
      for (int c = 0; c < 64; ++c) wrow[c] = (_Float16)0.f;
    } else {
      int hv = r - 208, h = hv >> 6, vv = hv & 63;
      // row position (vhi,kg,r2) holds v_actual = kg*16 + vhi*4 + r2
      int v = (((vv >> 2) & 3) << 4) | (((vv >> 4) & 3) << 2) | (vv & 3);
      for (int c = 0; c < 64; ++c)
        wrow[c] = (_Float16)(((c >> 4) == h) ? stats[c] * lcq[c & 15][v] : 0.f);
      for (int k = 0; k < 16; ++k) bias += stats[64 + h * 16 + k] * lcq[k][v];
    }
    Bbig[b * M2_ + r] = bias;
  }
}

// ---------------- K5: fused S-GEMM + y_c-GEMM + banded conv ----------
// 16x4 pixel tile, 4 waves (wave = pixel row). LDS 53,248 B -> 3 blk/CU.
// XOR-swizzled vn LDS, [pix][tap*4+h] s LDS (stride 196, ssum via shfl).
__global__ __launch_bounds__(256, 3) void k_fused(
                        const _Float16* __restrict__ q16,
                        const _Float16* __restrict__ v16,
                        const float* __restrict__ stats,
                        const _Float16* __restrict__ Wbig,
                        const float* __restrict__ Bbig,
                        float* __restrict__ out){
  __shared__ _Float16 vn_s[220 * 64];      // 28160 B, XOR-swizzled (16B gran)
  __shared__ _Float16 s_s[4][16][196];     // 25088 B, [wave][pix][tap*4+h]

  const int b  = blockIdx.z;
  const int x0 = blockIdx.x * 16;
  const int y0 = blockIdx.y * 4;
  const int tid = threadIdx.x;
  const int lane = tid & 63, wid = tid >> 6;
  const int cl = lane & 15, kg = lane >> 4;
  const size_t bN = (size_t)b * N_;

  // ---- vn halo staging: 220 pos x 64 v, coalesced 16B loads ----
  for (int idx = tid; idx < 1760; idx += 256){
    int pos = idx >> 3, c8 = (idx & 7) << 3;
    int yy = pos / 22, xx = pos - yy * 22;
    int gy = y0 + yy - 3, gx = x0 + xx - 3;
    f16x8 val;
    #pragma unroll
    for (int j = 0; j < 8; ++j) val[j] = (_Float16)0.f;
    if ((unsigned)gy < 64u && (unsigned)gx < 64u)
      val = *reinterpret_cast<const f16x8*>(v16 + ((bN + gy * 64 + gx) << 6) + c8);
    int e = (pos << 6) + c8;
    *reinterpret_cast<f16x8*>(&vn_s[e ^ ((pos & 7) << 3)]) = val;
  }

  // ---- MFMA phase: 29 row-tiles for this wave's 16 pixels ----
  const int pix = (y0 + wid) * 64 + x0 + cl;
  const _Float16* qp = q16 + ((bN + pix) << 6);
  f16x8 bfrag0 = *reinterpret_cast<const f16x8*>(qp + kg * 8);
  f16x8 bfrag1 = *reinterpret_cast<const f16x8*>(qp + 32 + kg * 8);
  const _Float16* Wb = Wbig + ((size_t)b * M2_ << 6);
  const float* Bb = Bbig + b * M2_;

  f32x4 acc[29];
  #pragma unroll
  for (int m = 0; m < 29; ++m){ acc[m][0]=0.f; acc[m][1]=0.f; acc[m][2]=0.f; acc[m][3]=0.f; }

  #pragma unroll
  for (int m = 0; m < 29; ++m){
    f16x8 a0 = *reinterpret_cast<const f16x8*>(Wb + ((m * 16 + cl) << 6) + kg * 8);
    f16x8 a1 = *reinterpret_cast<const f16x8*>(Wb + ((m * 16 + cl) << 6) + 32 + kg * 8);
    acc[m] = __builtin_amdgcn_mfma_f32_16x16x32_f16(a0, bfrag0, acc[m], 0, 0, 0);
    acc[m] = __builtin_amdgcn_mfma_f32_16x16x32_f16(a1, bfrag1, acc[m], 0, 0, 0);
  }

  // ---- ssum rows (196..199) live in lane 16+cl's acc[12]: shfl ----
  float ssum[4];
  #pragma unroll
  for (int h = 0; h < 4; ++h)
    ssum[h] = __shfl(acc[12][h], 16 + cl, 64) + Bb[196 + h];

  // ---- S rows (+bias) -> per-wave LDS, layout [pix][tap*4+h] ----
  #pragma unroll
  for (int m = 0; m < 13; ++m){
    #pragma unroll
    for (int r = 0; r < 4; ++r){
      const int row = m * 16 + kg * 4 + r;
      if (row < SROWS_){
        const int pos = (row % 49) * 4 + row / 49;
        s_s[wid][cl][pos] = (_Float16)(acc[m][r] + Bb[row]);
      }
    }
  }
  __syncthreads();

  // ---- band phase: 49 taps, thread owns pixel cl x v in [kg*16,+16) ----
  f16x2 accB[4][8];
  #pragma unroll
  for (int h = 0; h < 4; ++h)
    #pragma unroll
    for (int j = 0; j < 8; ++j){ accB[h][j][0] = (_Float16)0.f; accB[h][j][1] = (_Float16)0.f; }

  const _Float16* srow = &s_s[wid][cl][0];
  #pragma unroll
  for (int dy = 0; dy < 7; ++dy){
    #pragma unroll
    for (int dx = 0; dx < 7; ++dx){
      const int tap = dy * 7 + dx;
      const int pos = (wid + dy) * 22 + (cl + dx);
      f16x4 s4 = *reinterpret_cast<const f16x4*>(srow + tap * 4);
      const int esw = ((pos << 6) + (kg << 4)) ^ ((pos & 7) << 3);
      f16x8 va = *reinterpret_cast<const f16x8*>(&vn_s[esw]);
      f16x8 vb = *reinterpret_cast<const f16x8*>(&vn_s[esw ^ 8]);
      #pragma unroll
      for (int h = 0; h < 4; ++h){
        f16x2 sh; sh[0] = s4[h]; sh[1] = s4[h];
        f16x2 p0 = __builtin_shufflevector(va, va, 0, 1);
        f16x2 p1 = __builtin_shufflevector(va, va, 2, 3);
        f16x2 p2 = __builtin_shufflevector(va, va, 4, 5);
        f16x2 p3 = __builtin_shufflevector(va, va, 6, 7);
        f16x2 p4 = __builtin_shufflevector(vb, vb, 0, 1);
        f16x2 p5 = __builtin_shufflevector(vb, vb, 2, 3);
        f16x2 p6 = __builtin_shufflevector(vb, vb, 4, 5);
        f16x2 p7 = __builtin_shufflevector(vb, vb, 6, 7);
        accB[h][0] = sh * p0 + accB[h][0];
        accB[h][1] = sh * p1 + accB[h][1];
        accB[h][2] = sh * p2 + accB[h][2];
        accB[h][3] = sh * p3 + accB[h][3];
        accB[h][4] = sh * p4 + accB[h][4];
        accB[h][5] = sh * p5 + accB[h][5];
        accB[h][6] = sh * p6 + accB[h][6];
        accB[h][7] = sh * p7 + accB[h][7];
      }
    }
  }

  // ---- merge y_c (MFMA acc, permuted rows) + a_v*band + c_v*ssum ----
  float* ob = out + ((size_t)b * 256) * N_ + pix;
  #pragma unroll
  for (int h = 0; h < 4; ++h){
    #pragma unroll
    for (int vhi = 0; vhi < 4; ++vhi){
      const int m = 13 + h * 4 + vhi;
      f32x4 av = *reinterpret_cast<const f32x4*>(stats + 128 + kg * 16 + vhi * 4);
      f32x4 cv = *reinterpret_cast<const f32x4*>(stats + 192 + kg * 16 + vhi * 4);
      #pragma unroll
      for (int r = 0; r < 4; ++r){
        const int j = vhi * 4 + r;                  // v offset within kg chunk
        const int ch = h * 64 + kg * 16 + j;        // actual output channel
        const float band = (float)accB[h][j >> 1][j & 1];
        ob[(size_t)ch * N_] = acc[m][r] + Bb[208 + h * 64 + vhi * 16 + kg * 4 + r]
                              + av[r] * band + cv[r] * ssum[h];
      }
    }
  }
}

extern "C" void kernel_launch(void* const* d_in, const int* in_sizes, int n_in,
                              void* d_out, int out_size, void* d_ws, size_t ws_size,
                              hipStream_t stream){
  (void)in_sizes; (void)n_in; (void)out_size; (void)ws_size;
  const float* x  = (const float*)d_in[0];
  const float* Wq = (const float*)d_in[1];
  const float* Wk = (const float*)d_in[2];
  const float* Wv = (const float*)d_in[3];
  const float* gq = (const float*)d_in[4];
  const float* bq = (const float*)d_in[5];
  const float* gv = (const float*)d_in[6];
  const float* bv = (const float*)d_in[7];
  const float* pw = (const float*)d_in[8];
  const float* pb = (const float*)d_in[9];
  float* out = (float*)d_out;

  char* ws = (char*)d_ws;
  size_t off = 0;
  _Float16* Wcat = (_Float16*)(ws + off);  off += 131072;                     // 73,728 used
  _Float16* q16  = (_Float16*)(ws + off);  off += (size_t)NT_ * 64 * 2;       // 8,388,608
  _Float16* v16  = (_Float16*)(ws + off);  off += (size_t)NT_ * 64 * 2;       // 8,388,608
  _Float16* ek16 = (_Float16*)(ws + off);  off += (size_t)NT_ * 16 * 2;       // 2,097,152
  _Float16* Wbig = (_Float16*)(ws + off);  off += (size_t)B_ * M2_ * 64 * 2;  // 950,272
  float*    Bbig = (float*)(ws + off);     off += (size_t)B_ * M2_ * 4 + 2048;// 29,696
  float*    stats   = (float*)(ws + off);  off += 1024;
  float*    kstat   = (float*)(ws + off);  off += 1024;
  float*    lc_part = (float*)(ws + off);  off += (size_t)256 * 1024 * 4;     // 1,048,576
  float*    bnpart  = (float*)(ws + off);  off += (size_t)256 * 1024 * 4;     // 1,048,576
  float*    kpart   = (float*)(ws + off);  off += (size_t)256 * 64 * 4;       // 65,536

  k_pack_w <<<144, 256, 0, stream>>>(Wq, Wk, Wv, Wcat);
  k_proj   <<<1024, 256, 0, stream>>>(x, Wcat, q16, v16, ek16, bnpart, kpart);
  k_bn2    <<<129, 256, 0, stream>>>(bnpart, kpart, gq, bq, gv, bv, stats, kstat);
  k_lam1   <<<256, 256, 0, stream>>>(ek16, v16, kstat, lc_part);
  k_makeW  <<<16, 256, 0, stream>>>(stats, lc_part, pw, pb, Wbig, Bbig);
  dim3 g5(4, 16, 16);
  k_fused  <<<g5, 256, 0, stream>>>(q16, v16, stats, Wbig, Bbig, out);
}